// Round 1
// baseline (525.550 us; speedup 1.0000x reference)
//
#include <hip/hip_runtime.h>
#include <math.h>
#include <stdint.h>

#define TOKN 23040
#define BSZ 64
#define SEQ 360
#define DIM 256
#define NHD 8
#define HDD 32
#define MLPD 1024
#define NEGV -1e9f

typedef __attribute__((ext_vector_type(8))) short bf16x8;
typedef __attribute__((ext_vector_type(4))) float f32x4;

static __device__ __forceinline__ short f2bs(float f) {
  unsigned u = __builtin_bit_cast(unsigned, f);
  u += 0x7fffu + ((u >> 16) & 1u);
  return (short)(u >> 16);
}
static __device__ __forceinline__ float bf2f(short s) {
  unsigned u = ((unsigned)(unsigned short)s) << 16;
  return __builtin_bit_cast(float, u);
}

// ---------------- weight convert + transpose to bf16 [N][K] ----------------
__global__ __launch_bounds__(256) void convw_k(
    const float* __restrict__ wqkv, const float* __restrict__ wo,
    const float* __restrict__ w1, const float* __restrict__ w2,
    short* __restrict__ wqkvt, short* __restrict__ wot,
    short* __restrict__ w1t, short* __restrict__ w2t) {
  int id = blockIdx.x * 256 + threadIdx.x;
  if (id < 256 * 768) {  // wqkv [256][768] -> [768][256]
    int k = id / 768, n = id % 768;
    wqkvt[n * 256 + k] = f2bs(wqkv[id]);
  }
  if (id < 256 * 256) {  // wo [256][256] -> [256][256]^T
    int k = id >> 8, n = id & 255;
    wot[n * 256 + k] = f2bs(wo[id]);
  }
  if (id < 256 * 1024) {  // w1 [256][1024] -> [1024][256]
    int k = id >> 10, n = id & 1023;
    w1t[n * 256 + k] = f2bs(w1[id]);
  }
  if (id < 1024 * 256) {  // w2 [1024][256] -> [256][1024]
    int k = id >> 8, n = id & 255;
    w2t[n * 1024 + k] = f2bs(w2[id]);
  }
}

// ---------------- LN1 + router weight dot (fp32), xn -> bf16 ----------------
__global__ __launch_bounds__(64) void ln_router_k(
    const float* __restrict__ in, const float* __restrict__ g,
    const float* __restrict__ b, const float* __restrict__ wpw,
    const float* __restrict__ wpb, short* __restrict__ outn,
    float* __restrict__ wout) {
  int tok = blockIdx.x, lane = threadIdx.x;
  const float4 xv = *(const float4*)(in + (size_t)tok * DIM + lane * 4);
  float s = xv.x + xv.y + xv.z + xv.w;
  float s2 = xv.x * xv.x + xv.y * xv.y + xv.z * xv.z + xv.w * xv.w;
#pragma unroll
  for (int o = 1; o < 64; o <<= 1) { s += __shfl_xor(s, o); s2 += __shfl_xor(s2, o); }
  float m = s * (1.f / DIM);
  float var = fmaxf(s2 * (1.f / DIM) - m * m, 0.f);
  float rstd = rsqrtf(var + 1e-5f);
  float4 gv = *(const float4*)(g + lane * 4);
  float4 bv = *(const float4*)(b + lane * 4);
  unsigned r0 = (unsigned short)f2bs((xv.x - m) * rstd * gv.x + bv.x) |
                ((unsigned)(unsigned short)f2bs((xv.y - m) * rstd * gv.y + bv.y) << 16);
  unsigned r1 = (unsigned short)f2bs((xv.z - m) * rstd * gv.z + bv.z) |
                ((unsigned)(unsigned short)f2bs((xv.w - m) * rstd * gv.w + bv.w) << 16);
  uint2 pk; pk.x = r0; pk.y = r1;
  *(uint2*)(outn + (size_t)tok * DIM + lane * 4) = pk;
  float4 wv = *(const float4*)(wpw + lane * 4);
  float wd = xv.x * wv.x + xv.y * wv.y + xv.z * wv.z + xv.w * wv.w;
#pragma unroll
  for (int o = 1; o < 64; o <<= 1) wd += __shfl_xor(wd, o);
  if (lane == 0) wout[tok] = wd + wpb[0];
}

// ---------------- LN2 (fp32 in -> bf16 out) ----------------
__global__ __launch_bounds__(64) void ln_k(
    const float* __restrict__ in, const float* __restrict__ g,
    const float* __restrict__ b, short* __restrict__ outn) {
  int tok = blockIdx.x, lane = threadIdx.x;
  const float4 xv = *(const float4*)(in + (size_t)tok * DIM + lane * 4);
  float s = xv.x + xv.y + xv.z + xv.w;
  float s2 = xv.x * xv.x + xv.y * xv.y + xv.z * xv.z + xv.w * xv.w;
#pragma unroll
  for (int o = 1; o < 64; o <<= 1) { s += __shfl_xor(s, o); s2 += __shfl_xor(s2, o); }
  float m = s * (1.f / DIM);
  float var = fmaxf(s2 * (1.f / DIM) - m * m, 0.f);
  float rstd = rsqrtf(var + 1e-5f);
  float4 gv = *(const float4*)(g + lane * 4);
  float4 bv = *(const float4*)(b + lane * 4);
  unsigned r0 = (unsigned short)f2bs((xv.x - m) * rstd * gv.x + bv.x) |
                ((unsigned)(unsigned short)f2bs((xv.y - m) * rstd * gv.y + bv.y) << 16);
  unsigned r1 = (unsigned short)f2bs((xv.z - m) * rstd * gv.z + bv.z) |
                ((unsigned)(unsigned short)f2bs((xv.w - m) * rstd * gv.w + bv.w) << 16);
  uint2 pk; pk.x = r0; pk.y = r1;
  *(uint2*)(outn + (size_t)tok * DIM + lane * 4) = pk;
}

// ---------------- router a1 GEMM (fp32, silu): H[M,128] = silu(x @ a1_w^T + b) ----------------
__global__ __launch_bounds__(256) void router_gemm_k(
    const float* __restrict__ x, const float* __restrict__ a1w,
    const float* __restrict__ a1b, float* __restrict__ H) {
  __shared__ __align__(16) float Xs[64][36];
  __shared__ __align__(16) float Ws[128][36];
  int m0 = blockIdx.x * 64;
  int t = threadIdx.x;
  int tx = t & 31, ty = t >> 5;  // tx: dim group (4 dims), ty: token group (8 tokens)
  float acc[8][4] = {};
  int r = t >> 2, c = (t & 3) * 8;
  int r2 = t >> 1, c2 = (t & 1) * 16;
  for (int k0 = 0; k0 < 256; k0 += 32) {
    *(float4*)&Xs[r][c] = *(const float4*)(x + (size_t)(m0 + r) * 256 + k0 + c);
    *(float4*)&Xs[r][c + 4] = *(const float4*)(x + (size_t)(m0 + r) * 256 + k0 + c + 4);
#pragma unroll
    for (int j = 0; j < 4; j++)
      *(float4*)&Ws[r2][c2 + j * 4] =
          *(const float4*)(a1w + (size_t)r2 * 256 + k0 + c2 + j * 4);
    __syncthreads();
    for (int kk = 0; kk < 32; kk++) {
      float wv[4], xv8[8];
#pragma unroll
      for (int j = 0; j < 4; j++) wv[j] = Ws[tx * 4 + j][kk];
#pragma unroll
      for (int i = 0; i < 8; i++) xv8[i] = Xs[ty * 8 + i][kk];
#pragma unroll
      for (int i = 0; i < 8; i++)
#pragma unroll
        for (int j = 0; j < 4; j++) acc[i][j] += xv8[i] * wv[j];
    }
    __syncthreads();
  }
#pragma unroll
  for (int i = 0; i < 8; i++)
#pragma unroll
    for (int j = 0; j < 4; j++) {
      int row = m0 + ty * 8 + i, dim = tx * 4 + j;
      float v = acc[i][j] + a1b[dim];
      float sg = 1.f / (1.f + expf(-v));
      H[(size_t)row * 128 + dim] = v * sg;
    }
}

// ---------------- router a2 + sel + attention bias row ----------------
__global__ __launch_bounds__(64) void router2_k(
    const float* __restrict__ H, const float* __restrict__ a2w,
    const float* __restrict__ a2b, const float* __restrict__ amask,
    int* __restrict__ sel, float* __restrict__ biasrow) {
  int tok = blockIdx.x, lane = threadIdx.x;
  float h0 = H[(size_t)tok * 128 + lane];
  float h1 = H[(size_t)tok * 128 + 64 + lane];
  float l0 = h0 * a2w[lane] + h1 * a2w[64 + lane];
  float l1 = h0 * a2w[128 + lane] + h1 * a2w[192 + lane];
#pragma unroll
  for (int o = 1; o < 64; o <<= 1) { l0 += __shfl_xor(l0, o); l1 += __shfl_xor(l1, o); }
  if (lane == 0) {
    l0 += a2b[0]; l1 += a2b[1];
    int s = (l1 > l0) ? 1 : 0;
    sel[tok] = s;
    biasrow[tok] = amask[tok] + (s ? 0.f : NEGV);
  }
}

// ---------------- avg_selected ----------------
__global__ __launch_bounds__(256) void finalize_k(const int* __restrict__ sel,
                                                  float* __restrict__ outavg) {
  __shared__ int wsum[4];
  int t = threadIdx.x;
  int s = 0;
  for (int i = t; i < TOKN; i += 256) s += sel[i];
#pragma unroll
  for (int o = 1; o < 64; o <<= 1) s += __shfl_xor(s, o);
  if ((t & 63) == 0) wsum[t >> 6] = s;
  __syncthreads();
  if (t == 0) outavg[0] = (float)(wsum[0] + wsum[1] + wsum[2] + wsum[3]) / 64.0f;
}

// ---------------- bf16 MFMA GEMM: C[M,N] = epilogue(A[M,K] @ Bt[N,K]^T + bias) ----------------
// MODE 0: outb = bf16(v)                      (qkv)
// MODE 1: outf = v + res                      (h1 = ctx@wo + bo + x)
// MODE 2: outb = bf16(gelu_tanh(v))           (mlp act)
// MODE 3: outf = sel ? (v+res)*wgt : xin      (final output)
template <int MODE>
__global__ __launch_bounds__(256) void gemm_bt_k(
    const short* __restrict__ A, const short* __restrict__ Bt,
    const float* __restrict__ bias, const float* __restrict__ res,
    const int* __restrict__ sel, const float* __restrict__ wgt,
    const float* __restrict__ xin, short* __restrict__ outb,
    float* __restrict__ outf, int Ndim, int Kdim) {
  __shared__ __align__(16) short As[64][40];
  __shared__ __align__(16) short Bs[64][40];
  int m0 = blockIdx.y * 64;
  int n0 = blockIdx.x * 64;
  int t = threadIdx.x;
  int wave = t >> 6, lane = t & 63;
  int l15 = lane & 15, quad = lane >> 4;
  int wr = (wave >> 1) * 32, wc = (wave & 1) * 32;
  int srow = t >> 2, scg = (t & 3) * 8;

  f32x4 acc[2][2];
#pragma unroll
  for (int i = 0; i < 2; i++)
#pragma unroll
    for (int j = 0; j < 2; j++)
#pragma unroll
      for (int r = 0; r < 4; r++) acc[i][j][r] = 0.f;

  for (int k0 = 0; k0 < Kdim; k0 += 32) {
    int4 av = *(const int4*)(A + (size_t)(m0 + srow) * Kdim + k0 + scg);
    int4 bv = *(const int4*)(Bt + (size_t)(n0 + srow) * Kdim + k0 + scg);
    *(int4*)&As[srow][scg] = av;
    *(int4*)&Bs[srow][scg] = bv;
    __syncthreads();
    bf16x8 af[2], bfr[2];
    af[0] = *(const bf16x8*)&As[wr + l15][quad * 8];
    af[1] = *(const bf16x8*)&As[wr + 16 + l15][quad * 8];
    bfr[0] = *(const bf16x8*)&Bs[wc + l15][quad * 8];
    bfr[1] = *(const bf16x8*)&Bs[wc + 16 + l15][quad * 8];
#pragma unroll
    for (int i = 0; i < 2; i++)
#pragma unroll
      for (int j = 0; j < 2; j++)
        acc[i][j] = __builtin_amdgcn_mfma_f32_16x16x32_bf16(af[i], bfr[j],
                                                            acc[i][j], 0, 0, 0);
    __syncthreads();
  }

#pragma unroll
  for (int i = 0; i < 2; i++)
#pragma unroll
    for (int j = 0; j < 2; j++) {
      int col = n0 + wc + j * 16 + l15;
      float bcol = bias[col];
#pragma unroll
      for (int r = 0; r < 4; r++) {
        int row = m0 + wr + i * 16 + quad * 4 + r;
        float v = acc[i][j][r] + bcol;
        size_t idx = (size_t)row * Ndim + col;
        if (MODE == 0) {
          outb[idx] = f2bs(v);
        } else if (MODE == 1) {
          outf[idx] = v + res[idx];
        } else if (MODE == 2) {
          float u = 0.7978845608028654f * (v + 0.044715f * v * v * v);
          float e = __expf(2.f * u);
          float th = 1.f - 2.f / (e + 1.f);
          outb[idx] = f2bs(0.5f * v * (1.f + th));
        } else {
          float bo_ = v + res[idx];
          float o = sel[row] ? bo_ * wgt[row] : xin[idx];
          outf[idx] = o;
        }
      }
    }
}

// ---------------- attention: one block per (b,h), 2 waves ----------------
__global__ __launch_bounds__(128) void attn_k(const short* __restrict__ qkv,
                                              const float* __restrict__ biasrow,
                                              short* __restrict__ ctx) {
  __shared__ __align__(16) short Vt[32][392];
  __shared__ __align__(16) short Sw[2][16][392];
  __shared__ float ls[384];
  int bh = blockIdx.x, bb = bh >> 3, h = bh & 7;
  int t = threadIdx.x;
  size_t base = (size_t)bb * SEQ * 768;
  // stage V transposed (pad keys 360..383 with zeros)
  for (int i = t; i < 1536; i += 128) {
    int key = i >> 2, cg = (i & 3) * 8;
    if (key < SEQ) {
      union { int4 v; short s[8]; } u;
      u.v = *(const int4*)(qkv + base + (size_t)key * 768 + 512 + h * 32 + cg);
#pragma unroll
      for (int j = 0; j < 8; j++) Vt[cg + j][key] = u.s[j];
    } else {
#pragma unroll
      for (int j = 0; j < 8; j++) Vt[cg + j][key] = 0;
    }
  }
  for (int i = t; i < 384; i += 128) ls[i] = (i < SEQ) ? biasrow[bb * SEQ + i] : NEGV;
  __syncthreads();

  int wave = t >> 6, lane = t & 63;
  int l15 = lane & 15, quad = lane >> 4;
  // 24 q-tiles of 16 rows (384 padded), 12 per wave -> uniform __syncthreads
  for (int qt = wave; qt < 24; qt += 2) {
    int q0 = qt * 16, qrow = q0 + l15;
    bf16x8 qf;
#pragma unroll
    for (int j = 0; j < 8; j++) qf[j] = 0;
    if (qrow < SEQ)
      qf = *(const bf16x8*)(qkv + base + (size_t)qrow * 768 + h * 32 + quad * 8);
    // scores for this q-tile, all 384 (padded) keys
    for (int kt = 0; kt < 384; kt += 16) {
      int key = kt + l15;
      bf16x8 kf;
#pragma unroll
      for (int j = 0; j < 8; j++) kf[j] = 0;
      if (key < SEQ)
        kf = *(const bf16x8*)(qkv + base + (size_t)key * 768 + 256 + h * 32 + quad * 8);
      f32x4 s4;
#pragma unroll
      for (int r = 0; r < 4; r++) s4[r] = 0.f;
      s4 = __builtin_amdgcn_mfma_f32_16x16x32_bf16(qf, kf, s4, 0, 0, 0);
      float bl = ls[key];
#pragma unroll
      for (int r = 0; r < 4; r++)
        Sw[wave][quad * 4 + r][key] = f2bs(s4[r] * 0.17677669529663687f + bl);
    }
    __syncthreads();
    // softmax: 4 lanes per query row
    int rr = lane >> 2, c0 = lane & 3;
    float mx = -3.0e38f;
    for (int c = c0; c < 384; c += 4) mx = fmaxf(mx, bf2f(Sw[wave][rr][c]));
    mx = fmaxf(mx, __shfl_xor(mx, 1));
    mx = fmaxf(mx, __shfl_xor(mx, 2));
    float sum = 0.f;
    for (int c = c0; c < 384; c += 4) {
      float pv = __expf(bf2f(Sw[wave][rr][c]) - mx);
      sum += pv;
      Sw[wave][rr][c] = f2bs(pv);
    }
    sum += __shfl_xor(sum, 1);
    sum += __shfl_xor(sum, 2);
    float inv = 1.f / sum;
    for (int c = c0; c < 384; c += 4)
      Sw[wave][rr][c] = f2bs(bf2f(Sw[wave][rr][c]) * inv);
    __syncthreads();
    // PV
    f32x4 o0, o1;
#pragma unroll
    for (int r = 0; r < 4; r++) { o0[r] = 0.f; o1[r] = 0.f; }
    for (int kt = 0; kt < 384; kt += 32) {
      bf16x8 pf = *(const bf16x8*)&Sw[wave][l15][kt + quad * 8];
      bf16x8 v0 = *(const bf16x8*)&Vt[l15][kt + quad * 8];
      bf16x8 v1 = *(const bf16x8*)&Vt[16 + l15][kt + quad * 8];
      o0 = __builtin_amdgcn_mfma_f32_16x16x32_bf16(pf, v0, o0, 0, 0, 0);
      o1 = __builtin_amdgcn_mfma_f32_16x16x32_bf16(pf, v1, o1, 0, 0, 0);
    }
#pragma unroll
    for (int r = 0; r < 4; r++) {
      int q = q0 + quad * 4 + r;
      if (q < SEQ) {
        size_t cb = ((size_t)bb * SEQ + q) * 256 + h * 32;
        ctx[cb + l15] = f2bs(o0[r]);
        ctx[cb + 16 + l15] = f2bs(o1[r]);
      }
    }
    __syncthreads();
  }
}

extern "C" void kernel_launch(void* const* d_in, const int* in_sizes, int n_in,
                              void* d_out, int out_size, void* d_ws,
                              size_t ws_size, hipStream_t stream) {
  const float* x = (const float*)d_in[0];
  const float* amask = (const float*)d_in[1];
  const float* wp_w = (const float*)d_in[2];
  const float* wp_b = (const float*)d_in[3];
  const float* a1_w = (const float*)d_in[4];
  const float* a1_b = (const float*)d_in[5];
  const float* a2_w = (const float*)d_in[6];
  const float* a2_b = (const float*)d_in[7];
  const float* ln1_g = (const float*)d_in[8];
  const float* ln1_b = (const float*)d_in[9];
  const float* wqkv = (const float*)d_in[10];
  const float* bqkv = (const float*)d_in[11];
  const float* wo = (const float*)d_in[12];
  const float* bo = (const float*)d_in[13];
  const float* ln2_g = (const float*)d_in[14];
  const float* ln2_b = (const float*)d_in[15];
  const float* w1 = (const float*)d_in[16];
  const float* b1 = (const float*)d_in[17];
  const float* w2 = (const float*)d_in[18];
  const float* b2 = (const float*)d_in[19];
  float* out = (float*)d_out;

  uint8_t* p = (uint8_t*)d_ws;
  float* weightsv = (float*)p; p += (size_t)TOKN * 4;
  int* selv = (int*)p;         p += (size_t)TOKN * 4;
  float* biasrowv = (float*)p; p += (size_t)TOKN * 4;
  short* wqkvt = (short*)p;    p += (size_t)768 * 256 * 2;
  short* wot = (short*)p;      p += (size_t)256 * 256 * 2;
  short* w1t = (short*)p;      p += (size_t)1024 * 256 * 2;
  short* w2t = (short*)p;      p += (size_t)256 * 1024 * 2;
  float* h1v = (float*)p;      p += (size_t)TOKN * 256 * 4;
  short* h2nv = (short*)p;     p += (size_t)TOKN * 256 * 2;
  uint8_t* ctxH = p;           p += (size_t)TOKN * 256 * 2;  // ctx bf16 aliases H f32[TOKN][128]
  short* ctxv = (short*)ctxH;
  float* Hv = (float*)ctxH;
  uint8_t* R = p;  // [xn bf16 TOKN*256][qkv bf16 TOKN*768], later reused as act bf16 TOKN*1024
  short* xnv = (short*)R;
  short* qkvv = (short*)(R + (size_t)TOKN * 256 * 2);
  short* actv = (short*)R;

  // 1. weight convert+transpose
  convw_k<<<dim3(1024), dim3(256), 0, stream>>>(wqkv, wo, w1, w2, wqkvt, wot, w1t, w2t);
  // 2. LN1 + router scalar weight
  ln_router_k<<<dim3(TOKN), dim3(64), 0, stream>>>(x, ln1_g, ln1_b, wp_w, wp_b, xnv, weightsv);
  // 3. router a1 GEMM (fp32, silu)
  router_gemm_k<<<dim3(360), dim3(256), 0, stream>>>(x, a1_w, a1_b, Hv);
  // 4. router a2 -> sel, bias row
  router2_k<<<dim3(TOKN), dim3(64), 0, stream>>>(Hv, a2_w, a2_b, amask, selv, biasrowv);
  // 5. avg_selected -> out[last]
  finalize_k<<<dim3(1), dim3(256), 0, stream>>>(selv, out + (size_t)TOKN * 256);
  // 6. qkv GEMM (bf16 out)
  gemm_bt_k<0><<<dim3(12, 360), dim3(256), 0, stream>>>(
      xnv, wqkvt, bqkv, nullptr, nullptr, nullptr, nullptr, qkvv, nullptr, 768, 256);
  // 7. attention
  attn_k<<<dim3(512), dim3(128), 0, stream>>>(qkvv, biasrowv, ctxv);
  // 8. wo GEMM + residual -> h1 (fp32)
  gemm_bt_k<1><<<dim3(4, 360), dim3(256), 0, stream>>>(
      ctxv, wot, bo, x, nullptr, nullptr, nullptr, nullptr, h1v, 256, 256);
  // 9. LN2
  ln_k<<<dim3(TOKN), dim3(64), 0, stream>>>(h1v, ln2_g, ln2_b, h2nv);
  // 10. mlp up GEMM + gelu (bf16 out)
  gemm_bt_k<2><<<dim3(16, 360), dim3(256), 0, stream>>>(
      h2nv, w1t, b1, nullptr, nullptr, nullptr, nullptr, actv, nullptr, 1024, 256);
  // 11. mlp down GEMM + residual + select/scale -> d_out
  gemm_bt_k<3><<<dim3(4, 360), dim3(256), 0, stream>>>(
      actv, w2t, b2, h1v, selv, weightsv, x, nullptr, out, 256, 1024);
}

// Round 2
// 473.127 us; speedup vs baseline: 1.1108x; 1.1108x over previous
//
#include <hip/hip_runtime.h>
#include <math.h>
#include <stdint.h>

#define TOKN 23040
#define BSZ 64
#define SEQ 360
#define DIM 256
#define NHD 8
#define HDD 32
#define MLPD 1024
#define NEGV -1e9f

typedef __attribute__((ext_vector_type(8))) short bf16x8;
typedef __attribute__((ext_vector_type(4))) float f32x4;

static __device__ __forceinline__ short f2bs(float f) {
  unsigned u = __builtin_bit_cast(unsigned, f);
  u += 0x7fffu + ((u >> 16) & 1u);
  return (short)(u >> 16);
}
static __device__ __forceinline__ float bf2f(short s) {
  unsigned u = ((unsigned)(unsigned short)s) << 16;
  return __builtin_bit_cast(float, u);
}
static __device__ __forceinline__ unsigned packbf(float a, float b) {
  return (unsigned)(unsigned short)f2bs(a) | ((unsigned)(unsigned short)f2bs(b) << 16);
}

// ---------------- weight convert + transpose to bf16 [N][K] ----------------
__global__ __launch_bounds__(256) void convw_k(
    const float* __restrict__ wqkv, const float* __restrict__ wo,
    const float* __restrict__ w1, const float* __restrict__ w2,
    short* __restrict__ wqkvt, short* __restrict__ wot,
    short* __restrict__ w1t, short* __restrict__ w2t) {
  int id = blockIdx.x * 256 + threadIdx.x;
  if (id < 256 * 768) {  // wqkv [256][768] -> [768][256]
    int k = id / 768, n = id % 768;
    wqkvt[n * 256 + k] = f2bs(wqkv[id]);
  }
  if (id < 256 * 256) {  // wo [256][256] -> [256][256]^T
    int k = id >> 8, n = id & 255;
    wot[n * 256 + k] = f2bs(wo[id]);
  }
  if (id < 256 * 1024) {  // w1 [256][1024] -> [1024][256]
    int k = id >> 10, n = id & 1023;
    w1t[n * 256 + k] = f2bs(w1[id]);
  }
  if (id < 1024 * 256) {  // w2 [1024][256] -> [256][1024]
    int k = id >> 8, n = id & 255;
    w2t[n * 1024 + k] = f2bs(w2[id]);
  }
}

// ---------------- LN1 + router weight dot (fp32), xn -> bf16 ----------------
__global__ __launch_bounds__(64) void ln_router_k(
    const float* __restrict__ in, const float* __restrict__ g,
    const float* __restrict__ b, const float* __restrict__ wpw,
    const float* __restrict__ wpb, short* __restrict__ outn,
    float* __restrict__ wout) {
  int tok = blockIdx.x, lane = threadIdx.x;
  const float4 xv = *(const float4*)(in + (size_t)tok * DIM + lane * 4);
  float s = xv.x + xv.y + xv.z + xv.w;
  float s2 = xv.x * xv.x + xv.y * xv.y + xv.z * xv.z + xv.w * xv.w;
#pragma unroll
  for (int o = 1; o < 64; o <<= 1) { s += __shfl_xor(s, o); s2 += __shfl_xor(s2, o); }
  float m = s * (1.f / DIM);
  float var = fmaxf(s2 * (1.f / DIM) - m * m, 0.f);
  float rstd = rsqrtf(var + 1e-5f);
  float4 gv = *(const float4*)(g + lane * 4);
  float4 bv = *(const float4*)(b + lane * 4);
  unsigned r0 = packbf((xv.x - m) * rstd * gv.x + bv.x, (xv.y - m) * rstd * gv.y + bv.y);
  unsigned r1 = packbf((xv.z - m) * rstd * gv.z + bv.z, (xv.w - m) * rstd * gv.w + bv.w);
  uint2 pk; pk.x = r0; pk.y = r1;
  *(uint2*)(outn + (size_t)tok * DIM + lane * 4) = pk;
  float4 wv = *(const float4*)(wpw + lane * 4);
  float wd = xv.x * wv.x + xv.y * wv.y + xv.z * wv.z + xv.w * wv.w;
#pragma unroll
  for (int o = 1; o < 64; o <<= 1) wd += __shfl_xor(wd, o);
  if (lane == 0) wout[tok] = wd + wpb[0];
}

// ---------------- LN2 (fp32 in -> bf16 out) ----------------
__global__ __launch_bounds__(64) void ln_k(
    const float* __restrict__ in, const float* __restrict__ g,
    const float* __restrict__ b, short* __restrict__ outn) {
  int tok = blockIdx.x, lane = threadIdx.x;
  const float4 xv = *(const float4*)(in + (size_t)tok * DIM + lane * 4);
  float s = xv.x + xv.y + xv.z + xv.w;
  float s2 = xv.x * xv.x + xv.y * xv.y + xv.z * xv.z + xv.w * xv.w;
#pragma unroll
  for (int o = 1; o < 64; o <<= 1) { s += __shfl_xor(s, o); s2 += __shfl_xor(s2, o); }
  float m = s * (1.f / DIM);
  float var = fmaxf(s2 * (1.f / DIM) - m * m, 0.f);
  float rstd = rsqrtf(var + 1e-5f);
  float4 gv = *(const float4*)(g + lane * 4);
  float4 bv = *(const float4*)(b + lane * 4);
  unsigned r0 = packbf((xv.x - m) * rstd * gv.x + bv.x, (xv.y - m) * rstd * gv.y + bv.y);
  unsigned r1 = packbf((xv.z - m) * rstd * gv.z + bv.z, (xv.w - m) * rstd * gv.w + bv.w);
  uint2 pk; pk.x = r0; pk.y = r1;
  *(uint2*)(outn + (size_t)tok * DIM + lane * 4) = pk;
}

// ---------------- router a1 GEMM (fp32, silu): H[M,128] = silu(x @ a1_w^T + b) ----------------
__global__ __launch_bounds__(256) void router_gemm_k(
    const float* __restrict__ x, const float* __restrict__ a1w,
    const float* __restrict__ a1b, float* __restrict__ H) {
  __shared__ __align__(16) float Xs[64][36];
  __shared__ __align__(16) float Ws[128][36];
  int m0 = blockIdx.x * 64;
  int t = threadIdx.x;
  int tx = t & 31, ty = t >> 5;
  float acc[8][4] = {};
  int r = t >> 2, c = (t & 3) * 8;
  int r2 = t >> 1, c2 = (t & 1) * 16;
  for (int k0 = 0; k0 < 256; k0 += 32) {
    *(float4*)&Xs[r][c] = *(const float4*)(x + (size_t)(m0 + r) * 256 + k0 + c);
    *(float4*)&Xs[r][c + 4] = *(const float4*)(x + (size_t)(m0 + r) * 256 + k0 + c + 4);
#pragma unroll
    for (int j = 0; j < 4; j++)
      *(float4*)&Ws[r2][c2 + j * 4] =
          *(const float4*)(a1w + (size_t)r2 * 256 + k0 + c2 + j * 4);
    __syncthreads();
    for (int kk = 0; kk < 32; kk++) {
      float wv[4], xv8[8];
#pragma unroll
      for (int j = 0; j < 4; j++) wv[j] = Ws[tx * 4 + j][kk];
#pragma unroll
      for (int i = 0; i < 8; i++) xv8[i] = Xs[ty * 8 + i][kk];
#pragma unroll
      for (int i = 0; i < 8; i++)
#pragma unroll
        for (int j = 0; j < 4; j++) acc[i][j] += xv8[i] * wv[j];
    }
    __syncthreads();
  }
#pragma unroll
  for (int i = 0; i < 8; i++)
#pragma unroll
    for (int j = 0; j < 4; j++) {
      int row = m0 + ty * 8 + i, dim = tx * 4 + j;
      float v = acc[i][j] + a1b[dim];
      float sg = 1.f / (1.f + expf(-v));
      H[(size_t)row * 128 + dim] = v * sg;
    }
}

// ---------------- router a2 + sel + attention bias row ----------------
__global__ __launch_bounds__(64) void router2_k(
    const float* __restrict__ H, const float* __restrict__ a2w,
    const float* __restrict__ a2b, const float* __restrict__ amask,
    int* __restrict__ sel, float* __restrict__ biasrow) {
  int tok = blockIdx.x, lane = threadIdx.x;
  float h0 = H[(size_t)tok * 128 + lane];
  float h1 = H[(size_t)tok * 128 + 64 + lane];
  float l0 = h0 * a2w[lane] + h1 * a2w[64 + lane];
  float l1 = h0 * a2w[128 + lane] + h1 * a2w[192 + lane];
#pragma unroll
  for (int o = 1; o < 64; o <<= 1) { l0 += __shfl_xor(l0, o); l1 += __shfl_xor(l1, o); }
  if (lane == 0) {
    l0 += a2b[0]; l1 += a2b[1];
    int s = (l1 > l0) ? 1 : 0;
    sel[tok] = s;
    biasrow[tok] = amask[tok] + (s ? 0.f : NEGV);
  }
}

// ---------------- avg_selected ----------------
__global__ __launch_bounds__(256) void finalize_k(const int* __restrict__ sel,
                                                  float* __restrict__ outavg) {
  __shared__ int wsum[4];
  int t = threadIdx.x;
  int s = 0;
  for (int i = t; i < TOKN; i += 256) s += sel[i];
#pragma unroll
  for (int o = 1; o < 64; o <<= 1) s += __shfl_xor(s, o);
  if ((t & 63) == 0) wsum[t >> 6] = s;
  __syncthreads();
  if (t == 0) outavg[0] = (float)(wsum[0] + wsum[1] + wsum[2] + wsum[3]) / 64.0f;
}

// ---------------- bf16 MFMA GEMM (unchanged, verified) ----------------
template <int MODE>
__global__ __launch_bounds__(256) void gemm_bt_k(
    const short* __restrict__ A, const short* __restrict__ Bt,
    const float* __restrict__ bias, const float* __restrict__ res,
    const int* __restrict__ sel, const float* __restrict__ wgt,
    const float* __restrict__ xin, short* __restrict__ outb,
    float* __restrict__ outf, int Ndim, int Kdim) {
  __shared__ __align__(16) short As[64][40];
  __shared__ __align__(16) short Bs[64][40];
  int m0 = blockIdx.y * 64;
  int n0 = blockIdx.x * 64;
  int t = threadIdx.x;
  int wave = t >> 6, lane = t & 63;
  int l15 = lane & 15, quad = lane >> 4;
  int wr = (wave >> 1) * 32, wc = (wave & 1) * 32;
  int srow = t >> 2, scg = (t & 3) * 8;

  f32x4 acc[2][2];
#pragma unroll
  for (int i = 0; i < 2; i++)
#pragma unroll
    for (int j = 0; j < 2; j++)
#pragma unroll
      for (int r = 0; r < 4; r++) acc[i][j][r] = 0.f;

  for (int k0 = 0; k0 < Kdim; k0 += 32) {
    int4 av = *(const int4*)(A + (size_t)(m0 + srow) * Kdim + k0 + scg);
    int4 bv = *(const int4*)(Bt + (size_t)(n0 + srow) * Kdim + k0 + scg);
    *(int4*)&As[srow][scg] = av;
    *(int4*)&Bs[srow][scg] = bv;
    __syncthreads();
    bf16x8 af[2], bfr[2];
    af[0] = *(const bf16x8*)&As[wr + l15][quad * 8];
    af[1] = *(const bf16x8*)&As[wr + 16 + l15][quad * 8];
    bfr[0] = *(const bf16x8*)&Bs[wc + l15][quad * 8];
    bfr[1] = *(const bf16x8*)&Bs[wc + 16 + l15][quad * 8];
#pragma unroll
    for (int i = 0; i < 2; i++)
#pragma unroll
      for (int j = 0; j < 2; j++)
        acc[i][j] = __builtin_amdgcn_mfma_f32_16x16x32_bf16(af[i], bfr[j],
                                                            acc[i][j], 0, 0, 0);
    __syncthreads();
  }

#pragma unroll
  for (int i = 0; i < 2; i++)
#pragma unroll
    for (int j = 0; j < 2; j++) {
      int col = n0 + wc + j * 16 + l15;
      float bcol = bias[col];
#pragma unroll
      for (int r = 0; r < 4; r++) {
        int row = m0 + wr + i * 16 + quad * 4 + r;
        float v = acc[i][j][r] + bcol;
        size_t idx = (size_t)row * Ndim + col;
        if (MODE == 0) {
          outb[idx] = f2bs(v);
        } else if (MODE == 1) {
          outf[idx] = v + res[idx];
        } else if (MODE == 2) {
          float u = 0.7978845608028654f * (v + 0.044715f * v * v * v);
          float e = __expf(2.f * u);
          float th = 1.f - 2.f / (e + 1.f);
          outb[idx] = f2bs(0.5f * v * (1.f + th));
        } else {
          float bo_ = v + res[idx];
          float o = sel[row] ? bo_ * wgt[row] : xin[idx];
          outf[idx] = o;
        }
      }
    }
}

// ---------------- attention v2: register softmax + bpermute P-transpose ----------------
// grid: (b*8+h)*2 + qhalf -> 1024 blocks, 256 threads (4 waves)
// Per wave: q-tile of 16 queries. S^T = mfma(Kfrag, Qfrag): lane holds
// query q = lane&15 (col), keys kt*16 + quad*4 + r (rows). Softmax per
// query = per lane + shfl_xor(16,32). P -> PV B-frag via ds_bpermute.
// O^T = mfma(Vtfrag, Pfrag): col=q=lane&15, row=d -> 1/l is lane-scalar.
__global__ __launch_bounds__(256, 4) void attn_k(const short* __restrict__ qkv,
                                                 const float* __restrict__ biasrow,
                                                 short* __restrict__ ctx) {
  __shared__ __align__(16) short Vt[32][392];
  __shared__ __align__(16) float ls[384];
  int bh = blockIdx.x >> 1, qhalf = blockIdx.x & 1;
  int bb = bh >> 3, h = bh & 7;
  int t = threadIdx.x;
  size_t base = (size_t)bb * SEQ * 768;
  // stage V transposed [d][key], pad keys 360..383 with zeros
  for (int i = t; i < 1536; i += 256) {
    int key = i >> 2, cg = (i & 3) * 8;
    if (key < SEQ) {
      union { int4 v; short s[8]; } u;
      u.v = *(const int4*)(qkv + base + (size_t)key * 768 + 512 + h * 32 + cg);
#pragma unroll
      for (int j = 0; j < 8; j++) Vt[cg + j][key] = u.s[j];
    } else {
#pragma unroll
      for (int j = 0; j < 8; j++) Vt[cg + j][key] = 0;
    }
  }
  for (int i = t; i < 384; i += 256) ls[i] = (i < SEQ) ? biasrow[bb * SEQ + i] : NEGV;
  __syncthreads();

  int wave = t >> 6, lane = t & 63;
  int ql = lane & 15, quad = lane >> 4;
  int addr0 = (((quad & 1) * 2) * 16 + ql) * 4;  // bpermute byte addr, p<2
  int addr1 = addr0 + 64;                        // p>=2 (+16 lanes)
  bool hiq = quad >= 2;

  for (int ti = 0; ti < 3; ti++) {
    int qt = qhalf * 12 + wave * 3 + ti;
    if (qt >= 23) break;  // wave-uniform; no barriers inside loop
    int q0 = qt * 16;
    int qrow = q0 + ql;
    bf16x8 qf;
#pragma unroll
    for (int j = 0; j < 8; j++) qf[j] = 0;
    if (qrow < SEQ)
      qf = *(const bf16x8*)(qkv + base + (size_t)qrow * 768 + h * 32 + quad * 8);

    // ---- scores: 24 k-tiles of 16, packed bf16 pairs in registers ----
    unsigned pk[24][2];
    float mx = -3.0e38f;
#pragma unroll
    for (int kt = 0; kt < 24; kt++) {
      int key = kt * 16 + ql;
      bf16x8 kf;
#pragma unroll
      for (int j = 0; j < 8; j++) kf[j] = 0;
      if (key < SEQ)
        kf = *(const bf16x8*)(qkv + base + (size_t)key * 768 + 256 + h * 32 + quad * 8);
      f32x4 s4;
#pragma unroll
      for (int r = 0; r < 4; r++) s4[r] = 0.f;
      s4 = __builtin_amdgcn_mfma_f32_16x16x32_bf16(kf, qf, s4, 0, 0, 0);
      float4 lsv = *(const float4*)&ls[kt * 16 + quad * 4];  // quad-broadcast
      float sv0 = s4[0] * 0.17677669529663687f + lsv.x;
      float sv1 = s4[1] * 0.17677669529663687f + lsv.y;
      float sv2 = s4[2] * 0.17677669529663687f + lsv.z;
      float sv3 = s4[3] * 0.17677669529663687f + lsv.w;
      mx = fmaxf(mx, fmaxf(fmaxf(sv0, sv1), fmaxf(sv2, sv3)));
      pk[kt][0] = packbf(sv0, sv1);
      pk[kt][1] = packbf(sv2, sv3);
    }
    mx = fmaxf(mx, __shfl_xor(mx, 16));
    mx = fmaxf(mx, __shfl_xor(mx, 32));

    // ---- exp + sum (unnormalized P; normalize output instead) ----
    float lsum = 0.f;
#pragma unroll
    for (int kt = 0; kt < 24; kt++) {
#pragma unroll
      for (int pr = 0; pr < 2; pr++) {
        unsigned u = pk[kt][pr];
        float a = __builtin_bit_cast(float, u << 16);
        float b = __builtin_bit_cast(float, u & 0xffff0000u);
        float ea = __expf(a - mx);
        float eb = __expf(b - mx);
        lsum += ea + eb;
        pk[kt][pr] = packbf(ea, eb);
      }
    }
    lsum += __shfl_xor(lsum, 16);
    lsum += __shfl_xor(lsum, 32);
    float inv = 1.f / lsum;

    // ---- PV: O^T = mfma(Vt-frag, P-frag) over 12 chunks of 32 keys ----
    f32x4 o0, o1;
#pragma unroll
    for (int r = 0; r < 4; r++) { o0[r] = 0.f; o1[r] = 0.f; }
#pragma unroll
    for (int c = 0; c < 12; c++) {
      int s00 = __builtin_amdgcn_ds_bpermute(addr0, (int)pk[2 * c][0]);
      int s10 = __builtin_amdgcn_ds_bpermute(addr0, (int)pk[2 * c + 1][0]);
      int s01 = __builtin_amdgcn_ds_bpermute(addr0, (int)pk[2 * c][1]);
      int s11 = __builtin_amdgcn_ds_bpermute(addr0, (int)pk[2 * c + 1][1]);
      int s02 = __builtin_amdgcn_ds_bpermute(addr1, (int)pk[2 * c][0]);
      int s12 = __builtin_amdgcn_ds_bpermute(addr1, (int)pk[2 * c + 1][0]);
      int s03 = __builtin_amdgcn_ds_bpermute(addr1, (int)pk[2 * c][1]);
      int s13 = __builtin_amdgcn_ds_bpermute(addr1, (int)pk[2 * c + 1][1]);
      union { int i[4]; bf16x8 v; } pf;
      pf.i[0] = hiq ? s10 : s00;
      pf.i[1] = hiq ? s11 : s01;
      pf.i[2] = hiq ? s12 : s02;
      pf.i[3] = hiq ? s13 : s03;
      bf16x8 v0 = *(const bf16x8*)&Vt[ql][c * 32 + quad * 8];
      bf16x8 v1 = *(const bf16x8*)&Vt[16 + ql][c * 32 + quad * 8];
      o0 = __builtin_amdgcn_mfma_f32_16x16x32_bf16(v0, pf.v, o0, 0, 0, 0);
      o1 = __builtin_amdgcn_mfma_f32_16x16x32_bf16(v1, pf.v, o1, 0, 0, 0);
    }
    // ---- store: q = q0+ql (col), d = quad*4+r (+16) ----
    if (qrow < SEQ) {
      size_t cb = ((size_t)bb * SEQ + qrow) * 256 + h * 32;
      uint2 w0, w1;
      w0.x = packbf(o0[0] * inv, o0[1] * inv);
      w0.y = packbf(o0[2] * inv, o0[3] * inv);
      w1.x = packbf(o1[0] * inv, o1[1] * inv);
      w1.y = packbf(o1[2] * inv, o1[3] * inv);
      *(uint2*)(ctx + cb + quad * 4) = w0;
      *(uint2*)(ctx + cb + 16 + quad * 4) = w1;
    }
  }
}

extern "C" void kernel_launch(void* const* d_in, const int* in_sizes, int n_in,
                              void* d_out, int out_size, void* d_ws,
                              size_t ws_size, hipStream_t stream) {
  const float* x = (const float*)d_in[0];
  const float* amask = (const float*)d_in[1];
  const float* wp_w = (const float*)d_in[2];
  const float* wp_b = (const float*)d_in[3];
  const float* a1_w = (const float*)d_in[4];
  const float* a1_b = (const float*)d_in[5];
  const float* a2_w = (const float*)d_in[6];
  const float* a2_b = (const float*)d_in[7];
  const float* ln1_g = (const float*)d_in[8];
  const float* ln1_b = (const float*)d_in[9];
  const float* wqkv = (const float*)d_in[10];
  const float* bqkv = (const float*)d_in[11];
  const float* wo = (const float*)d_in[12];
  const float* bo = (const float*)d_in[13];
  const float* ln2_g = (const float*)d_in[14];
  const float* ln2_b = (const float*)d_in[15];
  const float* w1 = (const float*)d_in[16];
  const float* b1 = (const float*)d_in[17];
  const float* w2 = (const float*)d_in[18];
  const float* b2 = (const float*)d_in[19];
  float* out = (float*)d_out;

  uint8_t* p = (uint8_t*)d_ws;
  float* weightsv = (float*)p; p += (size_t)TOKN * 4;
  int* selv = (int*)p;         p += (size_t)TOKN * 4;
  float* biasrowv = (float*)p; p += (size_t)TOKN * 4;
  short* wqkvt = (short*)p;    p += (size_t)768 * 256 * 2;
  short* wot = (short*)p;      p += (size_t)256 * 256 * 2;
  short* w1t = (short*)p;      p += (size_t)1024 * 256 * 2;
  short* w2t = (short*)p;      p += (size_t)256 * 1024 * 2;
  float* h1v = (float*)p;      p += (size_t)TOKN * 256 * 4;
  short* h2nv = (short*)p;     p += (size_t)TOKN * 256 * 2;
  uint8_t* ctxH = p;           p += (size_t)TOKN * 256 * 2;
  short* ctxv = (short*)ctxH;
  float* Hv = (float*)ctxH;
  uint8_t* R = p;
  short* xnv = (short*)R;
  short* qkvv = (short*)(R + (size_t)TOKN * 256 * 2);
  short* actv = (short*)R;

  convw_k<<<dim3(1024), dim3(256), 0, stream>>>(wqkv, wo, w1, w2, wqkvt, wot, w1t, w2t);
  ln_router_k<<<dim3(TOKN), dim3(64), 0, stream>>>(x, ln1_g, ln1_b, wp_w, wp_b, xnv, weightsv);
  router_gemm_k<<<dim3(360), dim3(256), 0, stream>>>(x, a1_w, a1_b, Hv);
  router2_k<<<dim3(TOKN), dim3(64), 0, stream>>>(Hv, a2_w, a2_b, amask, selv, biasrowv);
  finalize_k<<<dim3(1), dim3(256), 0, stream>>>(selv, out + (size_t)TOKN * 256);
  gemm_bt_k<0><<<dim3(12, 360), dim3(256), 0, stream>>>(
      xnv, wqkvt, bqkv, nullptr, nullptr, nullptr, nullptr, qkvv, nullptr, 768, 256);
  attn_k<<<dim3(1024), dim3(256), 0, stream>>>(qkvv, biasrowv, ctxv);
  gemm_bt_k<1><<<dim3(4, 360), dim3(256), 0, stream>>>(
      ctxv, wot, bo, x, nullptr, nullptr, nullptr, nullptr, h1v, 256, 256);
  ln_k<<<dim3(TOKN), dim3(64), 0, stream>>>(h1v, ln2_g, ln2_b, h2nv);
  gemm_bt_k<2><<<dim3(16, 360), dim3(256), 0, stream>>>(
      h2nv, w1t, b1, nullptr, nullptr, nullptr, nullptr, actv, nullptr, 1024, 256);
  gemm_bt_k<3><<<dim3(4, 360), dim3(256), 0, stream>>>(
      actv, w2t, b2, h1v, selv, weightsv, x, nullptr, out, 256, 1024);
}

// Round 3
// 352.703 us; speedup vs baseline: 1.4901x; 1.3414x over previous
//
#include <hip/hip_runtime.h>
#include <math.h>
#include <stdint.h>

#define TOKN 23040
#define BSZ 64
#define SEQ 360
#define DIM 256
#define NHD 8
#define HDD 32
#define MLPD 1024
#define NEGV -1e9f

typedef __attribute__((ext_vector_type(8))) short bf16x8;
typedef __attribute__((ext_vector_type(4))) float f32x4;

static __device__ __forceinline__ short f2bs(float f) {
  unsigned u = __builtin_bit_cast(unsigned, f);
  u += 0x7fffu + ((u >> 16) & 1u);
  return (short)(u >> 16);
}
static __device__ __forceinline__ unsigned packbf(float a, float b) {
  return (unsigned)(unsigned short)f2bs(a) | ((unsigned)(unsigned short)f2bs(b) << 16);
}

// ---------------- weight convert + transpose to bf16 [N][K] ----------------
__global__ __launch_bounds__(256) void convw_k(
    const float* __restrict__ wqkv, const float* __restrict__ wo,
    const float* __restrict__ w1, const float* __restrict__ w2,
    short* __restrict__ wqkvt, short* __restrict__ wot,
    short* __restrict__ w1t, short* __restrict__ w2t) {
  int id = blockIdx.x * 256 + threadIdx.x;
  if (id < 256 * 768) {
    int k = id / 768, n = id % 768;
    wqkvt[n * 256 + k] = f2bs(wqkv[id]);
  }
  if (id < 256 * 256) {
    int k = id >> 8, n = id & 255;
    wot[n * 256 + k] = f2bs(wo[id]);
  }
  if (id < 256 * 1024) {
    int k = id >> 10, n = id & 1023;
    w1t[n * 256 + k] = f2bs(w1[id]);
  }
  if (id < 1024 * 256) {
    int k = id >> 8, n = id & 255;
    w2t[n * 1024 + k] = f2bs(w2[id]);
  }
}

// ---------------- LN1 + router weight dot (fp32), xn -> bf16 ----------------
__global__ __launch_bounds__(64) void ln_router_k(
    const float* __restrict__ in, const float* __restrict__ g,
    const float* __restrict__ b, const float* __restrict__ wpw,
    const float* __restrict__ wpb, short* __restrict__ outn,
    float* __restrict__ wout) {
  int tok = blockIdx.x, lane = threadIdx.x;
  const float4 xv = *(const float4*)(in + (size_t)tok * DIM + lane * 4);
  float s = xv.x + xv.y + xv.z + xv.w;
  float s2 = xv.x * xv.x + xv.y * xv.y + xv.z * xv.z + xv.w * xv.w;
#pragma unroll
  for (int o = 1; o < 64; o <<= 1) { s += __shfl_xor(s, o); s2 += __shfl_xor(s2, o); }
  float m = s * (1.f / DIM);
  float var = fmaxf(s2 * (1.f / DIM) - m * m, 0.f);
  float rstd = rsqrtf(var + 1e-5f);
  float4 gv = *(const float4*)(g + lane * 4);
  float4 bv = *(const float4*)(b + lane * 4);
  uint2 pk;
  pk.x = packbf((xv.x - m) * rstd * gv.x + bv.x, (xv.y - m) * rstd * gv.y + bv.y);
  pk.y = packbf((xv.z - m) * rstd * gv.z + bv.z, (xv.w - m) * rstd * gv.w + bv.w);
  *(uint2*)(outn + (size_t)tok * DIM + lane * 4) = pk;
  float4 wv = *(const float4*)(wpw + lane * 4);
  float wd = xv.x * wv.x + xv.y * wv.y + xv.z * wv.z + xv.w * wv.w;
#pragma unroll
  for (int o = 1; o < 64; o <<= 1) wd += __shfl_xor(wd, o);
  if (lane == 0) wout[tok] = wd + wpb[0];
}

// ---------------- LN2 (fp32 in -> bf16 out) ----------------
__global__ __launch_bounds__(64) void ln_k(
    const float* __restrict__ in, const float* __restrict__ g,
    const float* __restrict__ b, short* __restrict__ outn) {
  int tok = blockIdx.x, lane = threadIdx.x;
  const float4 xv = *(const float4*)(in + (size_t)tok * DIM + lane * 4);
  float s = xv.x + xv.y + xv.z + xv.w;
  float s2 = xv.x * xv.x + xv.y * xv.y + xv.z * xv.z + xv.w * xv.w;
#pragma unroll
  for (int o = 1; o < 64; o <<= 1) { s += __shfl_xor(s, o); s2 += __shfl_xor(s2, o); }
  float m = s * (1.f / DIM);
  float var = fmaxf(s2 * (1.f / DIM) - m * m, 0.f);
  float rstd = rsqrtf(var + 1e-5f);
  float4 gv = *(const float4*)(g + lane * 4);
  float4 bv = *(const float4*)(b + lane * 4);
  uint2 pk;
  pk.x = packbf((xv.x - m) * rstd * gv.x + bv.x, (xv.y - m) * rstd * gv.y + bv.y);
  pk.y = packbf((xv.z - m) * rstd * gv.z + bv.z, (xv.w - m) * rstd * gv.w + bv.w);
  *(uint2*)(outn + (size_t)tok * DIM + lane * 4) = pk;
}

// ---------------- router a1 GEMM (fp32, silu) ----------------
__global__ __launch_bounds__(256) void router_gemm_k(
    const float* __restrict__ x, const float* __restrict__ a1w,
    const float* __restrict__ a1b, float* __restrict__ H) {
  __shared__ __align__(16) float Xs[64][36];
  __shared__ __align__(16) float Ws[128][36];
  int m0 = blockIdx.x * 64;
  int t = threadIdx.x;
  int tx = t & 31, ty = t >> 5;
  float acc[8][4] = {};
  int r = t >> 2, c = (t & 3) * 8;
  int r2 = t >> 1, c2 = (t & 1) * 16;
  for (int k0 = 0; k0 < 256; k0 += 32) {
    *(float4*)&Xs[r][c] = *(const float4*)(x + (size_t)(m0 + r) * 256 + k0 + c);
    *(float4*)&Xs[r][c + 4] = *(const float4*)(x + (size_t)(m0 + r) * 256 + k0 + c + 4);
#pragma unroll
    for (int j = 0; j < 4; j++)
      *(float4*)&Ws[r2][c2 + j * 4] =
          *(const float4*)(a1w + (size_t)r2 * 256 + k0 + c2 + j * 4);
    __syncthreads();
    for (int kk = 0; kk < 32; kk++) {
      float wv[4], xv8[8];
#pragma unroll
      for (int j = 0; j < 4; j++) wv[j] = Ws[tx * 4 + j][kk];
#pragma unroll
      for (int i = 0; i < 8; i++) xv8[i] = Xs[ty * 8 + i][kk];
#pragma unroll
      for (int i = 0; i < 8; i++)
#pragma unroll
        for (int j = 0; j < 4; j++) acc[i][j] += xv8[i] * wv[j];
    }
    __syncthreads();
  }
#pragma unroll
  for (int i = 0; i < 8; i++)
#pragma unroll
    for (int j = 0; j < 4; j++) {
      int row = m0 + ty * 8 + i, dim = tx * 4 + j;
      float v = acc[i][j] + a1b[dim];
      float sg = 1.f / (1.f + expf(-v));
      H[(size_t)row * 128 + dim] = v * sg;
    }
}

// ---------------- router a2 + sel + attention bias row ----------------
__global__ __launch_bounds__(64) void router2_k(
    const float* __restrict__ H, const float* __restrict__ a2w,
    const float* __restrict__ a2b, const float* __restrict__ amask,
    int* __restrict__ sel, float* __restrict__ biasrow) {
  int tok = blockIdx.x, lane = threadIdx.x;
  float h0 = H[(size_t)tok * 128 + lane];
  float h1 = H[(size_t)tok * 128 + 64 + lane];
  float l0 = h0 * a2w[lane] + h1 * a2w[64 + lane];
  float l1 = h0 * a2w[128 + lane] + h1 * a2w[192 + lane];
#pragma unroll
  for (int o = 1; o < 64; o <<= 1) { l0 += __shfl_xor(l0, o); l1 += __shfl_xor(l1, o); }
  if (lane == 0) {
    l0 += a2b[0]; l1 += a2b[1];
    int s = (l1 > l0) ? 1 : 0;
    sel[tok] = s;
    biasrow[tok] = amask[tok] + (s ? 0.f : NEGV);
  }
}

// ---------------- avg_selected ----------------
__global__ __launch_bounds__(256) void finalize_k(const int* __restrict__ sel,
                                                  float* __restrict__ outavg) {
  __shared__ int wsum[4];
  int t = threadIdx.x;
  int s = 0;
  for (int i = t; i < TOKN; i += 256) s += sel[i];
#pragma unroll
  for (int o = 1; o < 64; o <<= 1) s += __shfl_xor(s, o);
  if ((t & 63) == 0) wsum[t >> 6] = s;
  __syncthreads();
  if (t == 0) outavg[0] = (float)(wsum[0] + wsum[1] + wsum[2] + wsum[3]) / 64.0f;
}

// ---------------- bf16 MFMA GEMM (unchanged, verified) ----------------
template <int MODE>
__global__ __launch_bounds__(256) void gemm_bt_k(
    const short* __restrict__ A, const short* __restrict__ Bt,
    const float* __restrict__ bias, const float* __restrict__ res,
    const int* __restrict__ sel, const float* __restrict__ wgt,
    const float* __restrict__ xin, short* __restrict__ outb,
    float* __restrict__ outf, int Ndim, int Kdim) {
  __shared__ __align__(16) short As[64][40];
  __shared__ __align__(16) short Bs[64][40];
  int m0 = blockIdx.y * 64;
  int n0 = blockIdx.x * 64;
  int t = threadIdx.x;
  int wave = t >> 6, lane = t & 63;
  int l15 = lane & 15, quad = lane >> 4;
  int wr = (wave >> 1) * 32, wc = (wave & 1) * 32;
  int srow = t >> 2, scg = (t & 3) * 8;

  f32x4 acc[2][2];
#pragma unroll
  for (int i = 0; i < 2; i++)
#pragma unroll
    for (int j = 0; j < 2; j++)
#pragma unroll
      for (int r = 0; r < 4; r++) acc[i][j][r] = 0.f;

  for (int k0 = 0; k0 < Kdim; k0 += 32) {
    int4 av = *(const int4*)(A + (size_t)(m0 + srow) * Kdim + k0 + scg);
    int4 bv = *(const int4*)(Bt + (size_t)(n0 + srow) * Kdim + k0 + scg);
    *(int4*)&As[srow][scg] = av;
    *(int4*)&Bs[srow][scg] = bv;
    __syncthreads();
    bf16x8 af[2], bfr[2];
    af[0] = *(const bf16x8*)&As[wr + l15][quad * 8];
    af[1] = *(const bf16x8*)&As[wr + 16 + l15][quad * 8];
    bfr[0] = *(const bf16x8*)&Bs[wc + l15][quad * 8];
    bfr[1] = *(const bf16x8*)&Bs[wc + 16 + l15][quad * 8];
#pragma unroll
    for (int i = 0; i < 2; i++)
#pragma unroll
      for (int j = 0; j < 2; j++)
        acc[i][j] = __builtin_amdgcn_mfma_f32_16x16x32_bf16(af[i], bfr[j],
                                                            acc[i][j], 0, 0, 0);
    __syncthreads();
  }

#pragma unroll
  for (int i = 0; i < 2; i++)
#pragma unroll
    for (int j = 0; j < 2; j++) {
      int col = n0 + wc + j * 16 + l15;
      float bcol = bias[col];
#pragma unroll
      for (int r = 0; r < 4; r++) {
        int row = m0 + wr + i * 16 + quad * 4 + r;
        float v = acc[i][j][r] + bcol;
        size_t idx = (size_t)row * Ndim + col;
        if (MODE == 0) {
          outb[idx] = f2bs(v);
        } else if (MODE == 1) {
          outf[idx] = v + res[idx];
        } else if (MODE == 2) {
          float u = 0.7978845608028654f * (v + 0.044715f * v * v * v);
          float e = __expf(2.f * u);
          float th = 1.f - 2.f / (e + 1.f);
          outb[idx] = f2bs(0.5f * v * (1.f + th));
        } else {
          float bo_ = v + res[idx];
          float o = sel[row] ? bo_ * wgt[row] : xin[idx];
          outf[idx] = o;
        }
      }
    }
}

// ---------------- attention v3: fused single-pass (no score array, no spill) ----------------
// grid: (b*8+h)*2 + qhalf -> 1024 blocks, 256 threads (4 waves).
// Per wave, per 16-query tile: iterate 12 chunks of 32 keys; each chunk:
// 2 S^T MFMAs -> bias+exp (no max-subtract; scores bounded) -> lsum
// -> 8x ds_bpermute P-transpose (verified mapping) -> 2 PV MFMAs.
// Softmax normalization applied once at the output store (1/lsum).
// Fully-deselected queries give 0*inf=NaN rows; final kernel's
// `sel ? . : xin` select drops them (row-independent GEMM).
__global__ __launch_bounds__(256) void attn_k(const short* __restrict__ qkv,
                                              const float* __restrict__ biasrow,
                                              short* __restrict__ ctx) {
  __shared__ __align__(16) short Vt[32][392];
  __shared__ __align__(16) float ls[384];
  int bh = blockIdx.x >> 1, qhalf = blockIdx.x & 1;
  int bb = bh >> 3, h = bh & 7;
  int t = threadIdx.x;
  size_t base = (size_t)bb * SEQ * 768;
  for (int i = t; i < 1536; i += 256) {
    int key = i >> 2, cg = (i & 3) * 8;
    if (key < SEQ) {
      union { int4 v; short s[8]; } u;
      u.v = *(const int4*)(qkv + base + (size_t)key * 768 + 512 + h * 32 + cg);
#pragma unroll
      for (int j = 0; j < 8; j++) Vt[cg + j][key] = u.s[j];
    } else {
#pragma unroll
      for (int j = 0; j < 8; j++) Vt[cg + j][key] = 0;
    }
  }
  for (int i = t; i < 384; i += 256) ls[i] = (i < SEQ) ? biasrow[bb * SEQ + i] : NEGV;
  __syncthreads();

  int wave = t >> 6, lane = t & 63;
  int ql = lane & 15, quad = lane >> 4;
  int addr0 = (((quad & 1) * 2) * 16 + ql) * 4;
  int addr1 = addr0 + 64;
  bool hiq = quad >= 2;

  for (int ti = 0; ti < 3; ti++) {
    int qt = qhalf * 12 + wave * 3 + ti;
    if (qt >= 23) break;  // wave-uniform
    int q0 = qt * 16;
    int qrow = q0 + ql;
    bf16x8 qf;
#pragma unroll
    for (int j = 0; j < 8; j++) qf[j] = 0;
    if (qrow < SEQ)
      qf = *(const bf16x8*)(qkv + base + (size_t)qrow * 768 + h * 32 + quad * 8);

    f32x4 o0, o1;
#pragma unroll
    for (int r = 0; r < 4; r++) { o0[r] = 0.f; o1[r] = 0.f; }
    float lsum = 0.f;

#pragma unroll 2
    for (int c = 0; c < 12; c++) {
      int keyA = c * 32 + ql;
      int keyB = keyA + 16;
      bf16x8 kfA, kfB;
#pragma unroll
      for (int j = 0; j < 8; j++) { kfA[j] = 0; kfB[j] = 0; }
      if (keyA < SEQ)
        kfA = *(const bf16x8*)(qkv + base + (size_t)keyA * 768 + 256 + h * 32 + quad * 8);
      if (keyB < SEQ)
        kfB = *(const bf16x8*)(qkv + base + (size_t)keyB * 768 + 256 + h * 32 + quad * 8);
      f32x4 sa, sb;
#pragma unroll
      for (int r = 0; r < 4; r++) { sa[r] = 0.f; sb[r] = 0.f; }
      sa = __builtin_amdgcn_mfma_f32_16x16x32_bf16(kfA, qf, sa, 0, 0, 0);
      sb = __builtin_amdgcn_mfma_f32_16x16x32_bf16(kfB, qf, sb, 0, 0, 0);
      float4 la = *(const float4*)&ls[c * 32 + quad * 4];
      float4 lb = *(const float4*)&ls[c * 32 + 16 + quad * 4];
      float ea0 = __expf(sa[0] * 0.17677669529663687f + la.x);
      float ea1 = __expf(sa[1] * 0.17677669529663687f + la.y);
      float ea2 = __expf(sa[2] * 0.17677669529663687f + la.z);
      float ea3 = __expf(sa[3] * 0.17677669529663687f + la.w);
      float eb0 = __expf(sb[0] * 0.17677669529663687f + lb.x);
      float eb1 = __expf(sb[1] * 0.17677669529663687f + lb.y);
      float eb2 = __expf(sb[2] * 0.17677669529663687f + lb.z);
      float eb3 = __expf(sb[3] * 0.17677669529663687f + lb.w);
      lsum += (ea0 + ea1) + (ea2 + ea3) + (eb0 + eb1) + (eb2 + eb3);
      unsigned pA0 = packbf(ea0, ea1), pA1 = packbf(ea2, ea3);
      unsigned pB0 = packbf(eb0, eb1), pB1 = packbf(eb2, eb3);
      int s00 = __builtin_amdgcn_ds_bpermute(addr0, (int)pA0);
      int s10 = __builtin_amdgcn_ds_bpermute(addr0, (int)pB0);
      int s01 = __builtin_amdgcn_ds_bpermute(addr0, (int)pA1);
      int s11 = __builtin_amdgcn_ds_bpermute(addr0, (int)pB1);
      int s02 = __builtin_amdgcn_ds_bpermute(addr1, (int)pA0);
      int s12 = __builtin_amdgcn_ds_bpermute(addr1, (int)pB0);
      int s03 = __builtin_amdgcn_ds_bpermute(addr1, (int)pA1);
      int s13 = __builtin_amdgcn_ds_bpermute(addr1, (int)pB1);
      union { int i[4]; bf16x8 v; } pf;
      pf.i[0] = hiq ? s10 : s00;
      pf.i[1] = hiq ? s11 : s01;
      pf.i[2] = hiq ? s12 : s02;
      pf.i[3] = hiq ? s13 : s03;
      bf16x8 v0 = *(const bf16x8*)&Vt[ql][c * 32 + quad * 8];
      bf16x8 v1 = *(const bf16x8*)&Vt[16 + ql][c * 32 + quad * 8];
      o0 = __builtin_amdgcn_mfma_f32_16x16x32_bf16(v0, pf.v, o0, 0, 0, 0);
      o1 = __builtin_amdgcn_mfma_f32_16x16x32_bf16(v1, pf.v, o1, 0, 0, 0);
    }
    lsum += __shfl_xor(lsum, 16);
    lsum += __shfl_xor(lsum, 32);
    float inv = 1.f / lsum;

    if (qrow < SEQ) {
      size_t cb = ((size_t)bb * SEQ + qrow) * 256 + h * 32;
      uint2 w0, w1;
      w0.x = packbf(o0[0] * inv, o0[1] * inv);
      w0.y = packbf(o0[2] * inv, o0[3] * inv);
      w1.x = packbf(o1[0] * inv, o1[1] * inv);
      w1.y = packbf(o1[2] * inv, o1[3] * inv);
      *(uint2*)(ctx + cb + quad * 4) = w0;
      *(uint2*)(ctx + cb + 16 + quad * 4) = w1;
    }
  }
}

extern "C" void kernel_launch(void* const* d_in, const int* in_sizes, int n_in,
                              void* d_out, int out_size, void* d_ws,
                              size_t ws_size, hipStream_t stream) {
  const float* x = (const float*)d_in[0];
  const float* amask = (const float*)d_in[1];
  const float* wp_w = (const float*)d_in[2];
  const float* wp_b = (const float*)d_in[3];
  const float* a1_w = (const float*)d_in[4];
  const float* a1_b = (const float*)d_in[5];
  const float* a2_w = (const float*)d_in[6];
  const float* a2_b = (const float*)d_in[7];
  const float* ln1_g = (const float*)d_in[8];
  const float* ln1_b = (const float*)d_in[9];
  const float* wqkv = (const float*)d_in[10];
  const float* bqkv = (const float*)d_in[11];
  const float* wo = (const float*)d_in[12];
  const float* bo = (const float*)d_in[13];
  const float* ln2_g = (const float*)d_in[14];
  const float* ln2_b = (const float*)d_in[15];
  const float* w1 = (const float*)d_in[16];
  const float* b1 = (const float*)d_in[17];
  const float* w2 = (const float*)d_in[18];
  const float* b2 = (const float*)d_in[19];
  float* out = (float*)d_out;

  uint8_t* p = (uint8_t*)d_ws;
  float* weightsv = (float*)p; p += (size_t)TOKN * 4;
  int* selv = (int*)p;         p += (size_t)TOKN * 4;
  float* biasrowv = (float*)p; p += (size_t)TOKN * 4;
  short* wqkvt = (short*)p;    p += (size_t)768 * 256 * 2;
  short* wot = (short*)p;      p += (size_t)256 * 256 * 2;
  short* w1t = (short*)p;      p += (size_t)1024 * 256 * 2;
  short* w2t = (short*)p;      p += (size_t)256 * 1024 * 2;
  float* h1v = (float*)p;      p += (size_t)TOKN * 256 * 4;
  short* h2nv = (short*)p;     p += (size_t)TOKN * 256 * 2;
  uint8_t* ctxH = p;           p += (size_t)TOKN * 256 * 2;
  short* ctxv = (short*)ctxH;
  float* Hv = (float*)ctxH;
  uint8_t* R = p;
  short* xnv = (short*)R;
  short* qkvv = (short*)(R + (size_t)TOKN * 256 * 2);
  short* actv = (short*)R;

  convw_k<<<dim3(1024), dim3(256), 0, stream>>>(wqkv, wo, w1, w2, wqkvt, wot, w1t, w2t);
  ln_router_k<<<dim3(TOKN), dim3(64), 0, stream>>>(x, ln1_g, ln1_b, wp_w, wp_b, xnv, weightsv);
  router_gemm_k<<<dim3(360), dim3(256), 0, stream>>>(x, a1_w, a1_b, Hv);
  router2_k<<<dim3(TOKN), dim3(64), 0, stream>>>(Hv, a2_w, a2_b, amask, selv, biasrowv);
  finalize_k<<<dim3(1), dim3(256), 0, stream>>>(selv, out + (size_t)TOKN * 256);
  gemm_bt_k<0><<<dim3(12, 360), dim3(256), 0, stream>>>(
      xnv, wqkvt, bqkv, nullptr, nullptr, nullptr, nullptr, qkvv, nullptr, 768, 256);
  attn_k<<<dim3(1024), dim3(256), 0, stream>>>(qkvv, biasrowv, ctxv);
  gemm_bt_k<1><<<dim3(4, 360), dim3(256), 0, stream>>>(
      ctxv, wot, bo, x, nullptr, nullptr, nullptr, nullptr, h1v, 256, 256);
  ln_k<<<dim3(TOKN), dim3(64), 0, stream>>>(h1v, ln2_g, ln2_b, h2nv);
  gemm_bt_k<2><<<dim3(16, 360), dim3(256), 0, stream>>>(
      h2nv, w1t, b1, nullptr, nullptr, nullptr, nullptr, actv, nullptr, 1024, 256);
  gemm_bt_k<3><<<dim3(4, 360), dim3(256), 0, stream>>>(
      actv, w2t, b2, h1v, selv, weightsv, x, nullptr, out, 256, 1024);
}

// Round 4
// 289.005 us; speedup vs baseline: 1.8185x; 1.2204x over previous
//
#include <hip/hip_runtime.h>
#include <math.h>
#include <stdint.h>

#define TOKN 23040
#define BSZ 64
#define SEQ 360
#define DIM 256
#define NHD 8
#define HDD 32
#define MLPD 1024
#define NEGV -1e9f

typedef __attribute__((ext_vector_type(8))) short bf16x8;
typedef __attribute__((ext_vector_type(4))) float f32x4;

static __device__ __forceinline__ short f2bs(float f) {
  unsigned u = __builtin_bit_cast(unsigned, f);
  u += 0x7fffu + ((u >> 16) & 1u);
  return (short)(u >> 16);
}
static __device__ __forceinline__ unsigned packbf(float a, float b) {
  return (unsigned)(unsigned short)f2bs(a) | ((unsigned)(unsigned short)f2bs(b) << 16);
}

// ---------------- weight convert + transpose to bf16 [N][K] ----------------
__global__ __launch_bounds__(256) void convw_k(
    const float* __restrict__ wqkv, const float* __restrict__ wo,
    const float* __restrict__ w1, const float* __restrict__ w2,
    short* __restrict__ wqkvt, short* __restrict__ wot,
    short* __restrict__ w1t, short* __restrict__ w2t) {
  int id = blockIdx.x * 256 + threadIdx.x;
  if (id < 256 * 768) {
    int k = id / 768, n = id % 768;
    wqkvt[n * 256 + k] = f2bs(wqkv[id]);
  }
  if (id < 256 * 256) {
    int k = id >> 8, n = id & 255;
    wot[n * 256 + k] = f2bs(wo[id]);
  }
  if (id < 256 * 1024) {
    int k = id >> 10, n = id & 1023;
    w1t[n * 256 + k] = f2bs(w1[id]);
  }
  if (id < 1024 * 256) {
    int k = id >> 8, n = id & 255;
    w2t[n * 1024 + k] = f2bs(w2[id]);
  }
}

// ---------------- LN1 + router weight dot (fp32), xn -> bf16, out=x passthrough ----------------
__global__ __launch_bounds__(64) void ln_router_k(
    const float* __restrict__ in, const float* __restrict__ g,
    const float* __restrict__ b, const float* __restrict__ wpw,
    const float* __restrict__ wpb, short* __restrict__ outn,
    float* __restrict__ wout, float* __restrict__ outx) {
  int tok = blockIdx.x, lane = threadIdx.x;
  const float4 xv = *(const float4*)(in + (size_t)tok * DIM + lane * 4);
  // passthrough: default output = x (selected rows overwritten by final GEMM)
  *(float4*)(outx + (size_t)tok * DIM + lane * 4) = xv;
  float s = xv.x + xv.y + xv.z + xv.w;
  float s2 = xv.x * xv.x + xv.y * xv.y + xv.z * xv.z + xv.w * xv.w;
#pragma unroll
  for (int o = 1; o < 64; o <<= 1) { s += __shfl_xor(s, o); s2 += __shfl_xor(s2, o); }
  float m = s * (1.f / DIM);
  float var = fmaxf(s2 * (1.f / DIM) - m * m, 0.f);
  float rstd = rsqrtf(var + 1e-5f);
  float4 gv = *(const float4*)(g + lane * 4);
  float4 bv = *(const float4*)(b + lane * 4);
  uint2 pk;
  pk.x = packbf((xv.x - m) * rstd * gv.x + bv.x, (xv.y - m) * rstd * gv.y + bv.y);
  pk.y = packbf((xv.z - m) * rstd * gv.z + bv.z, (xv.w - m) * rstd * gv.w + bv.w);
  *(uint2*)(outn + (size_t)tok * DIM + lane * 4) = pk;
  float4 wv = *(const float4*)(wpw + lane * 4);
  float wd = xv.x * wv.x + xv.y * wv.y + xv.z * wv.z + xv.w * wv.w;
#pragma unroll
  for (int o = 1; o < 64; o <<= 1) wd += __shfl_xor(wd, o);
  if (lane == 0) wout[tok] = wd + wpb[0];
}

// ---------------- LN2 (compact fp32 in -> bf16 out), early-exit past Mtot ----------------
__global__ __launch_bounds__(64) void ln_k(
    const float* __restrict__ in, const float* __restrict__ g,
    const float* __restrict__ b, const int* __restrict__ mtotp,
    short* __restrict__ outn) {
  int tok = blockIdx.x, lane = threadIdx.x;
  if (tok >= *mtotp) return;
  const float4 xv = *(const float4*)(in + (size_t)tok * DIM + lane * 4);
  float s = xv.x + xv.y + xv.z + xv.w;
  float s2 = xv.x * xv.x + xv.y * xv.y + xv.z * xv.z + xv.w * xv.w;
#pragma unroll
  for (int o = 1; o < 64; o <<= 1) { s += __shfl_xor(s, o); s2 += __shfl_xor(s2, o); }
  float m = s * (1.f / DIM);
  float var = fmaxf(s2 * (1.f / DIM) - m * m, 0.f);
  float rstd = rsqrtf(var + 1e-5f);
  float4 gv = *(const float4*)(g + lane * 4);
  float4 bv = *(const float4*)(b + lane * 4);
  uint2 pk;
  pk.x = packbf((xv.x - m) * rstd * gv.x + bv.x, (xv.y - m) * rstd * gv.y + bv.y);
  pk.y = packbf((xv.z - m) * rstd * gv.z + bv.z, (xv.w - m) * rstd * gv.w + bv.w);
  *(uint2*)(outn + (size_t)tok * DIM + lane * 4) = pk;
}

// ---------------- router a1 GEMM (fp32, silu) — unchanged (sel must be fp32-exact) ----------------
__global__ __launch_bounds__(256) void router_gemm_k(
    const float* __restrict__ x, const float* __restrict__ a1w,
    const float* __restrict__ a1b, float* __restrict__ H) {
  __shared__ __align__(16) float Xs[64][36];
  __shared__ __align__(16) float Ws[128][36];
  int m0 = blockIdx.x * 64;
  int t = threadIdx.x;
  int tx = t & 31, ty = t >> 5;
  float acc[8][4] = {};
  int r = t >> 2, c = (t & 3) * 8;
  int r2 = t >> 1, c2 = (t & 1) * 16;
  for (int k0 = 0; k0 < 256; k0 += 32) {
    *(float4*)&Xs[r][c] = *(const float4*)(x + (size_t)(m0 + r) * 256 + k0 + c);
    *(float4*)&Xs[r][c + 4] = *(const float4*)(x + (size_t)(m0 + r) * 256 + k0 + c + 4);
#pragma unroll
    for (int j = 0; j < 4; j++)
      *(float4*)&Ws[r2][c2 + j * 4] =
          *(const float4*)(a1w + (size_t)r2 * 256 + k0 + c2 + j * 4);
    __syncthreads();
    for (int kk = 0; kk < 32; kk++) {
      float wv[4], xv8[8];
#pragma unroll
      for (int j = 0; j < 4; j++) wv[j] = Ws[tx * 4 + j][kk];
#pragma unroll
      for (int i = 0; i < 8; i++) xv8[i] = Xs[ty * 8 + i][kk];
#pragma unroll
      for (int i = 0; i < 8; i++)
#pragma unroll
        for (int j = 0; j < 4; j++) acc[i][j] += xv8[i] * wv[j];
    }
    __syncthreads();
  }
#pragma unroll
  for (int i = 0; i < 8; i++)
#pragma unroll
    for (int j = 0; j < 4; j++) {
      int row = m0 + ty * 8 + i, dim = tx * 4 + j;
      float v = acc[i][j] + a1b[dim];
      float sg = 1.f / (1.f + expf(-v));
      H[(size_t)row * 128 + dim] = v * sg;
    }
}

// ---------------- router a2 + sel ----------------
__global__ __launch_bounds__(64) void router2_k(
    const float* __restrict__ H, const float* __restrict__ a2w,
    const float* __restrict__ a2b, int* __restrict__ sel) {
  int tok = blockIdx.x, lane = threadIdx.x;
  float h0 = H[(size_t)tok * 128 + lane];
  float h1 = H[(size_t)tok * 128 + 64 + lane];
  float l0 = h0 * a2w[lane] + h1 * a2w[64 + lane];
  float l1 = h0 * a2w[128 + lane] + h1 * a2w[192 + lane];
#pragma unroll
  for (int o = 1; o < 64; o <<= 1) { l0 += __shfl_xor(l0, o); l1 += __shfl_xor(l1, o); }
  if (lane == 0) {
    l0 += a2b[0]; l1 += a2b[1];
    sel[tok] = (l1 > l0) ? 1 : 0;
  }
}

// ---------------- compaction: per-batch scan / offsets / scatter ----------------
__global__ __launch_bounds__(512) void scanA_k(const int* __restrict__ sel,
                                               int* __restrict__ idxl,
                                               int* __restrict__ cnt) {
  __shared__ int sc[512];
  int b = blockIdx.x, t = threadIdx.x;
  int flag = (t < SEQ) ? sel[b * SEQ + t] : 0;
  sc[t] = flag;
  __syncthreads();
  int val = flag;
  for (int off = 1; off < 512; off <<= 1) {
    int add = (t >= off) ? sc[t - off] : 0;
    __syncthreads();
    val += add;
    sc[t] = val;
    __syncthreads();
  }
  if (flag) idxl[b * SEQ + (val - 1)] = t;
  if (t == 511) cnt[b] = val;
}

__global__ __launch_bounds__(512) void scanB_k(const int* __restrict__ cnt,
                                               int* __restrict__ startp,
                                               int* __restrict__ mtotp,
                                               int* __restrict__ g_idx) {
  __shared__ int sc[64];
  int t = threadIdx.x;
  if (t < 64) sc[t] = cnt[t];
  __syncthreads();
  if (t == 0) {
    int run = 0;
    for (int b = 0; b < 64; b++) { startp[b] = run; run += sc[b]; }
    *mtotp = run;
  }
  for (int i = t; i < TOKN; i += 512) g_idx[i] = 0;  // safe gather default
}

__global__ __launch_bounds__(512) void scanC_k(const int* __restrict__ idxl,
                                               const int* __restrict__ startp,
                                               const int* __restrict__ cnt,
                                               int* __restrict__ g_idx) {
  int b = blockIdx.x, t = threadIdx.x;
  int c = cnt[b], s0 = startp[b];
  for (int j = t; j < c; j += 512) g_idx[s0 + j] = b * SEQ + idxl[b * SEQ + j];
}

// ---------------- avg_selected ----------------
__global__ __launch_bounds__(256) void finalize_k(const int* __restrict__ sel,
                                                  float* __restrict__ outavg) {
  __shared__ int wsum[4];
  int t = threadIdx.x;
  int s = 0;
  for (int i = t; i < TOKN; i += 256) s += sel[i];
#pragma unroll
  for (int o = 1; o < 64; o <<= 1) s += __shfl_xor(s, o);
  if ((t & 63) == 0) wsum[t >> 6] = s;
  __syncthreads();
  if (t == 0) outavg[0] = (float)(wsum[0] + wsum[1] + wsum[2] + wsum[3]) / 64.0f;
}

// ---------------- bf16 MFMA GEMM over compact rows ----------------
// MODE 0: A gathered via g_idx; outb = bf16(v)               (qkv, compact out)
// MODE 1: outf = v + res[g_idx[row]]                         (h1 = ctx@wo+bo+x)
// MODE 2: outb = bf16(gelu(v))                               (mlp act)
// MODE 3: out[g_idx[row]] = (v + res[row])*wgt[g_idx[row]]   (scatter, row<Mt)
template <int MODE>
__global__ __launch_bounds__(256) void gemm_bt_k(
    const short* __restrict__ A, const short* __restrict__ Bt,
    const float* __restrict__ bias, const float* __restrict__ res,
    const float* __restrict__ wgt, const int* __restrict__ g_idx,
    const int* __restrict__ mtotp, short* __restrict__ outb,
    float* __restrict__ outf, int Ndim, int Kdim) {
  int Mt = *mtotp;
  int m0 = blockIdx.y * 64;
  if (m0 >= Mt) return;
  __shared__ __align__(16) short As[64][40];
  __shared__ __align__(16) short Bs[64][40];
  int n0 = blockIdx.x * 64;
  int t = threadIdx.x;
  int wave = t >> 6, lane = t & 63;
  int l15 = lane & 15, quad = lane >> 4;
  int wr = (wave >> 1) * 32, wc = (wave & 1) * 32;
  int srow = t >> 2, scg = (t & 3) * 8;
  int arow = (MODE == 0) ? g_idx[m0 + srow] : (m0 + srow);

  f32x4 acc[2][2];
#pragma unroll
  for (int i = 0; i < 2; i++)
#pragma unroll
    for (int j = 0; j < 2; j++)
#pragma unroll
      for (int r = 0; r < 4; r++) acc[i][j][r] = 0.f;

  for (int k0 = 0; k0 < Kdim; k0 += 32) {
    int4 av = *(const int4*)(A + (size_t)arow * Kdim + k0 + scg);
    int4 bv = *(const int4*)(Bt + (size_t)(n0 + srow) * Kdim + k0 + scg);
    *(int4*)&As[srow][scg] = av;
    *(int4*)&Bs[srow][scg] = bv;
    __syncthreads();
    bf16x8 af[2], bfr[2];
    af[0] = *(const bf16x8*)&As[wr + l15][quad * 8];
    af[1] = *(const bf16x8*)&As[wr + 16 + l15][quad * 8];
    bfr[0] = *(const bf16x8*)&Bs[wc + l15][quad * 8];
    bfr[1] = *(const bf16x8*)&Bs[wc + 16 + l15][quad * 8];
#pragma unroll
    for (int i = 0; i < 2; i++)
#pragma unroll
      for (int j = 0; j < 2; j++)
        acc[i][j] = __builtin_amdgcn_mfma_f32_16x16x32_bf16(af[i], bfr[j],
                                                            acc[i][j], 0, 0, 0);
    __syncthreads();
  }

#pragma unroll
  for (int i = 0; i < 2; i++)
#pragma unroll
    for (int j = 0; j < 2; j++) {
      int col = n0 + wc + j * 16 + l15;
      float bcol = bias[col];
#pragma unroll
      for (int r = 0; r < 4; r++) {
        int row = m0 + wr + i * 16 + quad * 4 + r;
        float v = acc[i][j][r] + bcol;
        size_t idx = (size_t)row * Ndim + col;
        if (MODE == 0) {
          outb[idx] = f2bs(v);
        } else if (MODE == 1) {
          int orig = g_idx[row];
          outf[idx] = v + res[(size_t)orig * 256 + col];
        } else if (MODE == 2) {
          float u = 0.7978845608028654f * (v + 0.044715f * v * v * v);
          float e = __expf(2.f * u);
          float th = 1.f - 2.f / (e + 1.f);
          outb[idx] = f2bs(0.5f * v * (1.f + th));
        } else {
          if (row < Mt) {
            int orig = g_idx[row];
            float o = (v + res[idx]) * wgt[orig];
            outf[(size_t)orig * 256 + col] = o;
          }
        }
      }
    }
}

// ---------------- attention v4: compact keys/queries, conflict-free V layout ----------------
// grid: (b*8+h)*2 + qhalf -> 1024 blocks, 256 threads (4 waves).
// All tokens in compact space are selected: no -1e9 bias; pad keys -> e=0.
// V^T staged fragment-linear: VF[(half*12+c)*64 + lane] (16B/lane, linear
// in lane => conflict-free ds_read_b128).
__global__ __launch_bounds__(256) void attn_k(
    const short* __restrict__ qkv, const float* __restrict__ amask,
    const int* __restrict__ g_idx, const int* __restrict__ startp,
    const int* __restrict__ cntp, short* __restrict__ ctx) {
  __shared__ __align__(16) short VF[2 * 12 * 64 * 8];
  __shared__ __align__(16) float ls[384];
  int bh = blockIdx.x >> 1, qhalf = blockIdx.x & 1;
  int bb = bh >> 3, h = bh & 7;
  int t = threadIdx.x;
  int start = startp[bb], cnt = cntp[bb];
  size_t base = (size_t)start * 768;
  for (int i = t; i < 1536; i += 256) {
    int k = i >> 2, cg = (i & 3) * 8;
    union { int4 v; short s[8]; } u;
    if (k < cnt) {
      u.v = *(const int4*)(qkv + base + (size_t)k * 768 + 512 + h * 32 + cg);
    } else {
      u.v = make_int4(0, 0, 0, 0);
    }
    int c = k >> 5, qd = (k >> 3) & 3, j = k & 7;
#pragma unroll
    for (int jj = 0; jj < 8; jj++) {
      int d = cg + jj;
      VF[((((d >> 4) * 12 + c) * 64) + qd * 16 + (d & 15)) * 8 + j] = u.s[jj];
    }
  }
  for (int i = t; i < 384; i += 256)
    ls[i] = (i < cnt) ? amask[g_idx[start + i]] : 0.f;
  __syncthreads();

  int wave = t >> 6, lane = t & 63;
  int ql = lane & 15, quad = lane >> 4;
  int addr0 = (((quad & 1) * 2) * 16 + ql) * 4;
  int addr1 = addr0 + 64;
  bool hiq = quad >= 2;
  int nt = (cnt + 15) >> 4;
  int nc = (cnt + 31) >> 5;

  for (int qt = qhalf + 2 * wave; qt < nt; qt += 8) {
    int q0 = qt * 16, qrow = q0 + ql;
    bf16x8 qf;
#pragma unroll
    for (int j = 0; j < 8; j++) qf[j] = 0;
    if (qrow < cnt)
      qf = *(const bf16x8*)(qkv + base + (size_t)qrow * 768 + h * 32 + quad * 8);

    f32x4 o0, o1;
#pragma unroll
    for (int r = 0; r < 4; r++) { o0[r] = 0.f; o1[r] = 0.f; }
    float lsum = 0.f;

    for (int c = 0; c < nc; c++) {
      int keyA = c * 32 + ql;
      int keyB = keyA + 16;
      bf16x8 kfA, kfB;
#pragma unroll
      for (int j = 0; j < 8; j++) { kfA[j] = 0; kfB[j] = 0; }
      if (keyA < cnt)
        kfA = *(const bf16x8*)(qkv + base + (size_t)keyA * 768 + 256 + h * 32 + quad * 8);
      if (keyB < cnt)
        kfB = *(const bf16x8*)(qkv + base + (size_t)keyB * 768 + 256 + h * 32 + quad * 8);
      f32x4 sa, sb;
#pragma unroll
      for (int r = 0; r < 4; r++) { sa[r] = 0.f; sb[r] = 0.f; }
      sa = __builtin_amdgcn_mfma_f32_16x16x32_bf16(kfA, qf, sa, 0, 0, 0);
      sb = __builtin_amdgcn_mfma_f32_16x16x32_bf16(kfB, qf, sb, 0, 0, 0);
      int kbase = c * 32 + quad * 4;  // lane's keys (rows of S^T)
      float4 la = *(const float4*)&ls[kbase];
      float4 lb = *(const float4*)&ls[kbase + 16];
      float ea0 = (kbase + 0 < cnt) ? __expf(sa[0] * 0.17677669529663687f + la.x) : 0.f;
      float ea1 = (kbase + 1 < cnt) ? __expf(sa[1] * 0.17677669529663687f + la.y) : 0.f;
      float ea2 = (kbase + 2 < cnt) ? __expf(sa[2] * 0.17677669529663687f + la.z) : 0.f;
      float ea3 = (kbase + 3 < cnt) ? __expf(sa[3] * 0.17677669529663687f + la.w) : 0.f;
      float eb0 = (kbase + 16 < cnt) ? __expf(sb[0] * 0.17677669529663687f + lb.x) : 0.f;
      float eb1 = (kbase + 17 < cnt) ? __expf(sb[1] * 0.17677669529663687f + lb.y) : 0.f;
      float eb2 = (kbase + 18 < cnt) ? __expf(sb[2] * 0.17677669529663687f + lb.z) : 0.f;
      float eb3 = (kbase + 19 < cnt) ? __expf(sb[3] * 0.17677669529663687f + lb.w) : 0.f;
      lsum += (ea0 + ea1) + (ea2 + ea3) + (eb0 + eb1) + (eb2 + eb3);
      unsigned pA0 = packbf(ea0, ea1), pA1 = packbf(ea2, ea3);
      unsigned pB0 = packbf(eb0, eb1), pB1 = packbf(eb2, eb3);
      int s00 = __builtin_amdgcn_ds_bpermute(addr0, (int)pA0);
      int s10 = __builtin_amdgcn_ds_bpermute(addr0, (int)pB0);
      int s01 = __builtin_amdgcn_ds_bpermute(addr0, (int)pA1);
      int s11 = __builtin_amdgcn_ds_bpermute(addr0, (int)pB1);
      int s02 = __builtin_amdgcn_ds_bpermute(addr1, (int)pA0);
      int s12 = __builtin_amdgcn_ds_bpermute(addr1, (int)pB0);
      int s03 = __builtin_amdgcn_ds_bpermute(addr1, (int)pA1);
      int s13 = __builtin_amdgcn_ds_bpermute(addr1, (int)pB1);
      union { int i[4]; bf16x8 v; } pf;
      pf.i[0] = hiq ? s10 : s00;
      pf.i[1] = hiq ? s11 : s01;
      pf.i[2] = hiq ? s12 : s02;
      pf.i[3] = hiq ? s13 : s03;
      bf16x8 v0 = *(const bf16x8*)&VF[(c * 64 + lane) * 8];
      bf16x8 v1 = *(const bf16x8*)&VF[((12 + c) * 64 + lane) * 8];
      o0 = __builtin_amdgcn_mfma_f32_16x16x32_bf16(v0, pf.v, o0, 0, 0, 0);
      o1 = __builtin_amdgcn_mfma_f32_16x16x32_bf16(v1, pf.v, o1, 0, 0, 0);
    }
    lsum += __shfl_xor(lsum, 16);
    lsum += __shfl_xor(lsum, 32);
    float inv = 1.f / lsum;

    if (qrow < cnt) {
      size_t cb = ((size_t)(start + qrow)) * 256 + h * 32;
      uint2 w0, w1;
      w0.x = packbf(o0[0] * inv, o0[1] * inv);
      w0.y = packbf(o0[2] * inv, o0[3] * inv);
      w1.x = packbf(o1[0] * inv, o1[1] * inv);
      w1.y = packbf(o1[2] * inv, o1[3] * inv);
      *(uint2*)(ctx + cb + quad * 4) = w0;
      *(uint2*)(ctx + cb + 16 + quad * 4) = w1;
    }
  }
}

extern "C" void kernel_launch(void* const* d_in, const int* in_sizes, int n_in,
                              void* d_out, int out_size, void* d_ws,
                              size_t ws_size, hipStream_t stream) {
  const float* x = (const float*)d_in[0];
  const float* amask = (const float*)d_in[1];
  const float* wp_w = (const float*)d_in[2];
  const float* wp_b = (const float*)d_in[3];
  const float* a1_w = (const float*)d_in[4];
  const float* a1_b = (const float*)d_in[5];
  const float* a2_w = (const float*)d_in[6];
  const float* a2_b = (const float*)d_in[7];
  const float* ln1_g = (const float*)d_in[8];
  const float* ln1_b = (const float*)d_in[9];
  const float* wqkv = (const float*)d_in[10];
  const float* bqkv = (const float*)d_in[11];
  const float* wo = (const float*)d_in[12];
  const float* bo = (const float*)d_in[13];
  const float* ln2_g = (const float*)d_in[14];
  const float* ln2_b = (const float*)d_in[15];
  const float* w1 = (const float*)d_in[16];
  const float* b1 = (const float*)d_in[17];
  const float* w2 = (const float*)d_in[18];
  const float* b2 = (const float*)d_in[19];
  float* out = (float*)d_out;

  uint8_t* p = (uint8_t*)d_ws;
  float* weightsv = (float*)p; p += (size_t)TOKN * 4;
  int* selv = (int*)p;         p += (size_t)TOKN * 4;
  int* idxlv = (int*)p;        p += (size_t)TOKN * 4;
  int* gidxv = (int*)p;        p += (size_t)TOKN * 4;
  int* cntv = (int*)p;         p += 64 * 4;
  int* startv = (int*)p;       p += 64 * 4;
  int* mtotv = (int*)p;        p += 64 * 4;
  short* wqkvt = (short*)p;    p += (size_t)768 * 256 * 2;
  short* wot = (short*)p;      p += (size_t)256 * 256 * 2;
  short* w1t = (short*)p;      p += (size_t)1024 * 256 * 2;
  short* w2t = (short*)p;      p += (size_t)256 * 1024 * 2;
  float* h1v = (float*)p;      p += (size_t)TOKN * 256 * 4;
  short* h2nv = (short*)p;     p += (size_t)TOKN * 256 * 2;
  uint8_t* ctxH = p;           p += (size_t)TOKN * 256 * 2;
  short* ctxv = (short*)ctxH;
  float* Hv = (float*)ctxH;
  uint8_t* R = p;
  short* xnv = (short*)R;
  short* qkvv = (short*)(R + (size_t)TOKN * 256 * 2);
  short* actv = (short*)R;

  convw_k<<<dim3(1024), dim3(256), 0, stream>>>(wqkv, wo, w1, w2, wqkvt, wot, w1t, w2t);
  ln_router_k<<<dim3(TOKN), dim3(64), 0, stream>>>(x, ln1_g, ln1_b, wp_w, wp_b, xnv,
                                                   weightsv, out);
  router_gemm_k<<<dim3(360), dim3(256), 0, stream>>>(x, a1_w, a1_b, Hv);
  router2_k<<<dim3(TOKN), dim3(64), 0, stream>>>(Hv, a2_w, a2_b, selv);
  scanA_k<<<dim3(64), dim3(512), 0, stream>>>(selv, idxlv, cntv);
  scanB_k<<<dim3(1), dim3(512), 0, stream>>>(cntv, startv, mtotv, gidxv);
  scanC_k<<<dim3(64), dim3(512), 0, stream>>>(idxlv, startv, cntv, gidxv);
  finalize_k<<<dim3(1), dim3(256), 0, stream>>>(selv, out + (size_t)TOKN * 256);
  gemm_bt_k<0><<<dim3(12, 360), dim3(256), 0, stream>>>(
      xnv, wqkvt, bqkv, nullptr, nullptr, gidxv, mtotv, qkvv, nullptr, 768, 256);
  attn_k<<<dim3(1024), dim3(256), 0, stream>>>(qkvv, amask, gidxv, startv, cntv, ctxv);
  gemm_bt_k<1><<<dim3(4, 360), dim3(256), 0, stream>>>(
      ctxv, wot, bo, x, nullptr, gidxv, mtotv, nullptr, h1v, 256, 256);
  ln_k<<<dim3(TOKN), dim3(64), 0, stream>>>(h1v, ln2_g, ln2_b, mtotv, h2nv);
  gemm_bt_k<2><<<dim3(16, 360), dim3(256), 0, stream>>>(
      h2nv, w1t, b1, nullptr, nullptr, gidxv, mtotv, actv, nullptr, 1024, 256);
  gemm_bt_k<3><<<dim3(4, 360), dim3(256), 0, stream>>>(
      actv, w2t, b2, h1v, weightsv, gidxv, mtotv, nullptr, out, 256, 1024);
}

// Round 5
// 261.293 us; speedup vs baseline: 2.0113x; 1.1061x over previous
//
#include <hip/hip_runtime.h>
#include <math.h>
#include <stdint.h>

#define TOKN 23040
#define BSZ 64
#define SEQ 360
#define DIM 256
#define NHD 8
#define HDD 32
#define MLPD 1024
#define NEGV -1e9f

typedef __attribute__((ext_vector_type(8))) short bf16x8;
typedef __attribute__((ext_vector_type(4))) float f32x4;

static __device__ __forceinline__ short f2bs(float f) {
  unsigned u = __builtin_bit_cast(unsigned, f);
  u += 0x7fffu + ((u >> 16) & 1u);
  return (short)(u >> 16);
}
static __device__ __forceinline__ unsigned packbf(float a, float b) {
  return (unsigned)(unsigned short)f2bs(a) | ((unsigned)(unsigned short)f2bs(b) << 16);
}

// ---------------- weight convert + transpose to bf16 [N][K] ----------------
__global__ __launch_bounds__(256) void convw_k(
    const float* __restrict__ wqkv, const float* __restrict__ wo,
    const float* __restrict__ w1, const float* __restrict__ w2,
    short* __restrict__ wqkvt, short* __restrict__ wot,
    short* __restrict__ w1t, short* __restrict__ w2t) {
  int id = blockIdx.x * 256 + threadIdx.x;
  if (id < 256 * 768) {
    int k = id / 768, n = id % 768;
    wqkvt[n * 256 + k] = f2bs(wqkv[id]);
  }
  if (id < 256 * 256) {
    int k = id >> 8, n = id & 255;
    wot[n * 256 + k] = f2bs(wo[id]);
  }
  if (id < 256 * 1024) {
    int k = id >> 10, n = id & 1023;
    w1t[n * 256 + k] = f2bs(w1[id]);
  }
  if (id < 1024 * 256) {
    int k = id >> 8, n = id & 255;
    w2t[n * 1024 + k] = f2bs(w2[id]);
  }
}

// ---------------- LN1 + router weight dot; 4 tokens/block (wave-per-token) ----------------
__global__ __launch_bounds__(256) void ln_router_k(
    const float* __restrict__ in, const float* __restrict__ g,
    const float* __restrict__ b, const float* __restrict__ wpw,
    const float* __restrict__ wpb, short* __restrict__ outn,
    float* __restrict__ wout, float* __restrict__ outx) {
  int tok = blockIdx.x * 4 + (threadIdx.x >> 6);
  int lane = threadIdx.x & 63;
  const float4 xv = *(const float4*)(in + (size_t)tok * DIM + lane * 4);
  *(float4*)(outx + (size_t)tok * DIM + lane * 4) = xv;  // passthrough default
  float s = xv.x + xv.y + xv.z + xv.w;
  float s2 = xv.x * xv.x + xv.y * xv.y + xv.z * xv.z + xv.w * xv.w;
#pragma unroll
  for (int o = 1; o < 64; o <<= 1) { s += __shfl_xor(s, o); s2 += __shfl_xor(s2, o); }
  float m = s * (1.f / DIM);
  float var = fmaxf(s2 * (1.f / DIM) - m * m, 0.f);
  float rstd = rsqrtf(var + 1e-5f);
  float4 gv = *(const float4*)(g + lane * 4);
  float4 bv = *(const float4*)(b + lane * 4);
  uint2 pk;
  pk.x = packbf((xv.x - m) * rstd * gv.x + bv.x, (xv.y - m) * rstd * gv.y + bv.y);
  pk.y = packbf((xv.z - m) * rstd * gv.z + bv.z, (xv.w - m) * rstd * gv.w + bv.w);
  *(uint2*)(outn + (size_t)tok * DIM + lane * 4) = pk;
  float4 wv = *(const float4*)(wpw + lane * 4);
  float wd = xv.x * wv.x + xv.y * wv.y + xv.z * wv.z + xv.w * wv.w;
#pragma unroll
  for (int o = 1; o < 64; o <<= 1) wd += __shfl_xor(wd, o);
  if (lane == 0) wout[tok] = wd + wpb[0];
}

// ---------------- LN2 compact; 4 tokens/block, wave early-exit on Mtot ----------------
__global__ __launch_bounds__(256) void ln_k(
    const float* __restrict__ in, const float* __restrict__ g,
    const float* __restrict__ b, const int* __restrict__ mtotp,
    short* __restrict__ outn) {
  int tok = blockIdx.x * 4 + (threadIdx.x >> 6);
  int lane = threadIdx.x & 63;
  if (tok >= *mtotp) return;  // wave-uniform, no barriers in kernel
  const float4 xv = *(const float4*)(in + (size_t)tok * DIM + lane * 4);
  float s = xv.x + xv.y + xv.z + xv.w;
  float s2 = xv.x * xv.x + xv.y * xv.y + xv.z * xv.z + xv.w * xv.w;
#pragma unroll
  for (int o = 1; o < 64; o <<= 1) { s += __shfl_xor(s, o); s2 += __shfl_xor(s2, o); }
  float m = s * (1.f / DIM);
  float var = fmaxf(s2 * (1.f / DIM) - m * m, 0.f);
  float rstd = rsqrtf(var + 1e-5f);
  float4 gv = *(const float4*)(g + lane * 4);
  float4 bv = *(const float4*)(b + lane * 4);
  uint2 pk;
  pk.x = packbf((xv.x - m) * rstd * gv.x + bv.x, (xv.y - m) * rstd * gv.y + bv.y);
  pk.y = packbf((xv.z - m) * rstd * gv.z + bv.z, (xv.w - m) * rstd * gv.w + bv.w);
  *(uint2*)(outn + (size_t)tok * DIM + lane * 4) = pk;
}

// ---------------- router fused: a1 GEMM (fp32) + silu + a2 + argmax -> sel ----------------
// Tiles k-major in LDS: compute reads are b128 lane-linear (WT) or
// broadcast (XT) -> conflict-free. Epilogue reduces l0/l1 over the 32-lane
// tx group (dims) via shfl_xor and writes sel directly (H never hits HBM).
__global__ __launch_bounds__(256) void router_gemm_k(
    const float* __restrict__ x, const float* __restrict__ a1w,
    const float* __restrict__ a1b, const float* __restrict__ a2w,
    const float* __restrict__ a2b, int* __restrict__ sel) {
  __shared__ __align__(16) float XT[32][65];
  __shared__ __align__(16) float WT[32][128];
  int m0 = blockIdx.x * 64;
  int t = threadIdx.x;
  int tx = t & 31, ty = t >> 5;  // tx: 4-dim group, ty: 8-token group
  float acc[8][4] = {};
  int r = t >> 2, c = (t & 3) * 8;    // X staging: row r, k-cols c..c+7
  int n2 = t >> 1, c2 = (t & 1) * 16; // W staging: dim n2, k-cols c2..c2+15
  for (int k0 = 0; k0 < 256; k0 += 32) {
    float4 xa = *(const float4*)(x + (size_t)(m0 + r) * 256 + k0 + c);
    float4 xb = *(const float4*)(x + (size_t)(m0 + r) * 256 + k0 + c + 4);
    XT[c + 0][r] = xa.x; XT[c + 1][r] = xa.y; XT[c + 2][r] = xa.z; XT[c + 3][r] = xa.w;
    XT[c + 4][r] = xb.x; XT[c + 5][r] = xb.y; XT[c + 6][r] = xb.z; XT[c + 7][r] = xb.w;
#pragma unroll
    for (int j = 0; j < 4; j++) {
      float4 wv = *(const float4*)(a1w + (size_t)n2 * 256 + k0 + c2 + j * 4);
      WT[c2 + j * 4 + 0][n2] = wv.x;
      WT[c2 + j * 4 + 1][n2] = wv.y;
      WT[c2 + j * 4 + 2][n2] = wv.z;
      WT[c2 + j * 4 + 3][n2] = wv.w;
    }
    __syncthreads();
#pragma unroll 8
    for (int kk = 0; kk < 32; kk++) {
      float4 wv4 = *(const float4*)&WT[kk][tx * 4];
      float4 x0 = *(const float4*)&XT[kk][ty * 8];
      float4 x1 = *(const float4*)&XT[kk][ty * 8 + 4];
      float xr[8] = {x0.x, x0.y, x0.z, x0.w, x1.x, x1.y, x1.z, x1.w};
      float wr[4] = {wv4.x, wv4.y, wv4.z, wv4.w};
#pragma unroll
      for (int i = 0; i < 8; i++)
#pragma unroll
        for (int j = 0; j < 4; j++) acc[i][j] += xr[i] * wr[j];
    }
    __syncthreads();
  }
  // epilogue: silu -> a2 partial dots -> tx-group reduce -> sel
  float b1v[4], a20[4], a21[4];
#pragma unroll
  for (int j = 0; j < 4; j++) {
    int dim = tx * 4 + j;
    b1v[j] = a1b[dim];
    a20[j] = a2w[dim];
    a21[j] = a2w[128 + dim];
  }
  float bias0 = a2b[0], bias1 = a2b[1];
#pragma unroll
  for (int i = 0; i < 8; i++) {
    float l0 = 0.f, l1 = 0.f;
#pragma unroll
    for (int j = 0; j < 4; j++) {
      float v = acc[i][j] + b1v[j];
      float h = v / (1.f + expf(-v));
      l0 += h * a20[j];
      l1 += h * a21[j];
    }
#pragma unroll
    for (int o = 1; o < 32; o <<= 1) { l0 += __shfl_xor(l0, o); l1 += __shfl_xor(l1, o); }
    if (tx == 0) sel[m0 + ty * 8 + i] = (l1 + bias1 > l0 + bias0) ? 1 : 0;
  }
}

// ---------------- compaction: per-batch scan / offsets / scatter ----------------
__global__ __launch_bounds__(512) void scanA_k(const int* __restrict__ sel,
                                               int* __restrict__ idxl,
                                               int* __restrict__ cnt) {
  __shared__ int sc[512];
  int b = blockIdx.x, t = threadIdx.x;
  int flag = (t < SEQ) ? sel[b * SEQ + t] : 0;
  sc[t] = flag;
  __syncthreads();
  int val = flag;
  for (int off = 1; off < 512; off <<= 1) {
    int add = (t >= off) ? sc[t - off] : 0;
    __syncthreads();
    val += add;
    sc[t] = val;
    __syncthreads();
  }
  if (flag) idxl[b * SEQ + (val - 1)] = t;
  if (t == 511) cnt[b] = val;
}

__global__ __launch_bounds__(512) void scanB_k(const int* __restrict__ cnt,
                                               int* __restrict__ startp,
                                               int* __restrict__ mtotp,
                                               int* __restrict__ g_idx,
                                               float* __restrict__ outavg) {
  __shared__ int sc[64];
  int t = threadIdx.x;
  if (t < 64) sc[t] = cnt[t];
  __syncthreads();
  if (t == 0) {
    int run = 0;
    for (int b = 0; b < 64; b++) { startp[b] = run; run += sc[b]; }
    *mtotp = run;
    outavg[0] = (float)run / 64.0f;  // avg_selected fused here
  }
  for (int i = t; i < TOKN; i += 512) g_idx[i] = 0;  // safe gather default
}

__global__ __launch_bounds__(512) void scanC_k(const int* __restrict__ idxl,
                                               const int* __restrict__ startp,
                                               const int* __restrict__ cnt,
                                               int* __restrict__ g_idx) {
  int b = blockIdx.x, t = threadIdx.x;
  int c = cnt[b], s0 = startp[b];
  for (int j = t; j < c; j += 512) g_idx[s0 + j] = b * SEQ + idxl[b * SEQ + j];
}

// ---------------- bf16 MFMA GEMM over compact rows ----------------
template <int MODE>
__global__ __launch_bounds__(256) void gemm_bt_k(
    const short* __restrict__ A, const short* __restrict__ Bt,
    const float* __restrict__ bias, const float* __restrict__ res,
    const float* __restrict__ wgt, const int* __restrict__ g_idx,
    const int* __restrict__ mtotp, short* __restrict__ outb,
    float* __restrict__ outf, int Ndim, int Kdim) {
  int Mt = *mtotp;
  int m0 = blockIdx.y * 64;
  if (m0 >= Mt) return;
  __shared__ __align__(16) short As[64][40];
  __shared__ __align__(16) short Bs[64][40];
  int n0 = blockIdx.x * 64;
  int t = threadIdx.x;
  int wave = t >> 6, lane = t & 63;
  int l15 = lane & 15, quad = lane >> 4;
  int wr = (wave >> 1) * 32, wc = (wave & 1) * 32;
  int srow = t >> 2, scg = (t & 3) * 8;
  int arow = (MODE == 0) ? g_idx[m0 + srow] : (m0 + srow);

  f32x4 acc[2][2];
#pragma unroll
  for (int i = 0; i < 2; i++)
#pragma unroll
    for (int j = 0; j < 2; j++)
#pragma unroll
      for (int r = 0; r < 4; r++) acc[i][j][r] = 0.f;

  for (int k0 = 0; k0 < Kdim; k0 += 32) {
    int4 av = *(const int4*)(A + (size_t)arow * Kdim + k0 + scg);
    int4 bv = *(const int4*)(Bt + (size_t)(n0 + srow) * Kdim + k0 + scg);
    *(int4*)&As[srow][scg] = av;
    *(int4*)&Bs[srow][scg] = bv;
    __syncthreads();
    bf16x8 af[2], bfr[2];
    af[0] = *(const bf16x8*)&As[wr + l15][quad * 8];
    af[1] = *(const bf16x8*)&As[wr + 16 + l15][quad * 8];
    bfr[0] = *(const bf16x8*)&Bs[wc + l15][quad * 8];
    bfr[1] = *(const bf16x8*)&Bs[wc + 16 + l15][quad * 8];
#pragma unroll
    for (int i = 0; i < 2; i++)
#pragma unroll
      for (int j = 0; j < 2; j++)
        acc[i][j] = __builtin_amdgcn_mfma_f32_16x16x32_bf16(af[i], bfr[j],
                                                            acc[i][j], 0, 0, 0);
    __syncthreads();
  }

#pragma unroll
  for (int i = 0; i < 2; i++)
#pragma unroll
    for (int j = 0; j < 2; j++) {
      int col = n0 + wc + j * 16 + l15;
      float bcol = bias[col];
#pragma unroll
      for (int r = 0; r < 4; r++) {
        int row = m0 + wr + i * 16 + quad * 4 + r;
        float v = acc[i][j][r] + bcol;
        size_t idx = (size_t)row * Ndim + col;
        if (MODE == 0) {
          outb[idx] = f2bs(v);
        } else if (MODE == 1) {
          int orig = g_idx[row];
          outf[idx] = v + res[(size_t)orig * 256 + col];
        } else if (MODE == 2) {
          float u = 0.7978845608028654f * (v + 0.044715f * v * v * v);
          float e = __expf(2.f * u);
          float th = 1.f - 2.f / (e + 1.f);
          outb[idx] = f2bs(0.5f * v * (1.f + th));
        } else {
          if (row < Mt) {
            int orig = g_idx[row];
            float o = (v + res[idx]) * wgt[orig];
            outf[(size_t)orig * 256 + col] = o;
          }
        }
      }
    }
}

// ---------------- attention (compact, conflict-free V layout) ----------------
__global__ __launch_bounds__(256) void attn_k(
    const short* __restrict__ qkv, const float* __restrict__ amask,
    const int* __restrict__ g_idx, const int* __restrict__ startp,
    const int* __restrict__ cntp, short* __restrict__ ctx) {
  __shared__ __align__(16) short VF[2 * 12 * 64 * 8];
  __shared__ __align__(16) float ls[384];
  int bh = blockIdx.x >> 1, qhalf = blockIdx.x & 1;
  int bb = bh >> 3, h = bh & 7;
  int t = threadIdx.x;
  int start = startp[bb], cnt = cntp[bb];
  size_t base = (size_t)start * 768;
  for (int i = t; i < 1536; i += 256) {
    int k = i >> 2, cg = (i & 3) * 8;
    union { int4 v; short s[8]; } u;
    if (k < cnt) {
      u.v = *(const int4*)(qkv + base + (size_t)k * 768 + 512 + h * 32 + cg);
    } else {
      u.v = make_int4(0, 0, 0, 0);
    }
    int c = k >> 5, qd = (k >> 3) & 3, j = k & 7;
#pragma unroll
    for (int jj = 0; jj < 8; jj++) {
      int d = cg + jj;
      VF[((((d >> 4) * 12 + c) * 64) + qd * 16 + (d & 15)) * 8 + j] = u.s[jj];
    }
  }
  for (int i = t; i < 384; i += 256)
    ls[i] = (i < cnt) ? amask[g_idx[start + i]] : 0.f;
  __syncthreads();

  int wave = t >> 6, lane = t & 63;
  int ql = lane & 15, quad = lane >> 4;
  int addr0 = (((quad & 1) * 2) * 16 + ql) * 4;
  int addr1 = addr0 + 64;
  bool hiq = quad >= 2;
  int nt = (cnt + 15) >> 4;
  int nc = (cnt + 31) >> 5;

  for (int qt = qhalf + 2 * wave; qt < nt; qt += 8) {
    int q0 = qt * 16, qrow = q0 + ql;
    bf16x8 qf;
#pragma unroll
    for (int j = 0; j < 8; j++) qf[j] = 0;
    if (qrow < cnt)
      qf = *(const bf16x8*)(qkv + base + (size_t)qrow * 768 + h * 32 + quad * 8);

    f32x4 o0, o1;
#pragma unroll
    for (int r = 0; r < 4; r++) { o0[r] = 0.f; o1[r] = 0.f; }
    float lsum = 0.f;

    for (int c = 0; c < nc; c++) {
      int keyA = c * 32 + ql;
      int keyB = keyA + 16;
      bf16x8 kfA, kfB;
#pragma unroll
      for (int j = 0; j < 8; j++) { kfA[j] = 0; kfB[j] = 0; }
      if (keyA < cnt)
        kfA = *(const bf16x8*)(qkv + base + (size_t)keyA * 768 + 256 + h * 32 + quad * 8);
      if (keyB < cnt)
        kfB = *(const bf16x8*)(qkv + base + (size_t)keyB * 768 + 256 + h * 32 + quad * 8);
      f32x4 sa, sb;
#pragma unroll
      for (int r = 0; r < 4; r++) { sa[r] = 0.f; sb[r] = 0.f; }
      sa = __builtin_amdgcn_mfma_f32_16x16x32_bf16(kfA, qf, sa, 0, 0, 0);
      sb = __builtin_amdgcn_mfma_f32_16x16x32_bf16(kfB, qf, sb, 0, 0, 0);
      int kbase = c * 32 + quad * 4;
      float4 la = *(const float4*)&ls[kbase];
      float4 lb = *(const float4*)&ls[kbase + 16];
      float ea0 = (kbase + 0 < cnt) ? __expf(sa[0] * 0.17677669529663687f + la.x) : 0.f;
      float ea1 = (kbase + 1 < cnt) ? __expf(sa[1] * 0.17677669529663687f + la.y) : 0.f;
      float ea2 = (kbase + 2 < cnt) ? __expf(sa[2] * 0.17677669529663687f + la.z) : 0.f;
      float ea3 = (kbase + 3 < cnt) ? __expf(sa[3] * 0.17677669529663687f + la.w) : 0.f;
      float eb0 = (kbase + 16 < cnt) ? __expf(sb[0] * 0.17677669529663687f + lb.x) : 0.f;
      float eb1 = (kbase + 17 < cnt) ? __expf(sb[1] * 0.17677669529663687f + lb.y) : 0.f;
      float eb2 = (kbase + 18 < cnt) ? __expf(sb[2] * 0.17677669529663687f + lb.z) : 0.f;
      float eb3 = (kbase + 19 < cnt) ? __expf(sb[3] * 0.17677669529663687f + lb.w) : 0.f;
      lsum += (ea0 + ea1) + (ea2 + ea3) + (eb0 + eb1) + (eb2 + eb3);
      unsigned pA0 = packbf(ea0, ea1), pA1 = packbf(ea2, ea3);
      unsigned pB0 = packbf(eb0, eb1), pB1 = packbf(eb2, eb3);
      int s00 = __builtin_amdgcn_ds_bpermute(addr0, (int)pA0);
      int s10 = __builtin_amdgcn_ds_bpermute(addr0, (int)pB0);
      int s01 = __builtin_amdgcn_ds_bpermute(addr0, (int)pA1);
      int s11 = __builtin_amdgcn_ds_bpermute(addr0, (int)pB1);
      int s02 = __builtin_amdgcn_ds_bpermute(addr1, (int)pA0);
      int s12 = __builtin_amdgcn_ds_bpermute(addr1, (int)pB0);
      int s03 = __builtin_amdgcn_ds_bpermute(addr1, (int)pA1);
      int s13 = __builtin_amdgcn_ds_bpermute(addr1, (int)pB1);
      union { int i[4]; bf16x8 v; } pf;
      pf.i[0] = hiq ? s10 : s00;
      pf.i[1] = hiq ? s11 : s01;
      pf.i[2] = hiq ? s12 : s02;
      pf.i[3] = hiq ? s13 : s03;
      bf16x8 v0 = *(const bf16x8*)&VF[(c * 64 + lane) * 8];
      bf16x8 v1 = *(const bf16x8*)&VF[((12 + c) * 64 + lane) * 8];
      o0 = __builtin_amdgcn_mfma_f32_16x16x32_bf16(v0, pf.v, o0, 0, 0, 0);
      o1 = __builtin_amdgcn_mfma_f32_16x16x32_bf16(v1, pf.v, o1, 0, 0, 0);
    }
    lsum += __shfl_xor(lsum, 16);
    lsum += __shfl_xor(lsum, 32);
    float inv = 1.f / lsum;

    if (qrow < cnt) {
      size_t cb = ((size_t)(start + qrow)) * 256 + h * 32;
      uint2 w0, w1;
      w0.x = packbf(o0[0] * inv, o0[1] * inv);
      w0.y = packbf(o0[2] * inv, o0[3] * inv);
      w1.x = packbf(o1[0] * inv, o1[1] * inv);
      w1.y = packbf(o1[2] * inv, o1[3] * inv);
      *(uint2*)(ctx + cb + quad * 4) = w0;
      *(uint2*)(ctx + cb + 16 + quad * 4) = w1;
    }
  }
}

extern "C" void kernel_launch(void* const* d_in, const int* in_sizes, int n_in,
                              void* d_out, int out_size, void* d_ws,
                              size_t ws_size, hipStream_t stream) {
  const float* x = (const float*)d_in[0];
  const float* amask = (const float*)d_in[1];
  const float* wp_w = (const float*)d_in[2];
  const float* wp_b = (const float*)d_in[3];
  const float* a1_w = (const float*)d_in[4];
  const float* a1_b = (const float*)d_in[5];
  const float* a2_w = (const float*)d_in[6];
  const float* a2_b = (const float*)d_in[7];
  const float* ln1_g = (const float*)d_in[8];
  const float* ln1_b = (const float*)d_in[9];
  const float* wqkv = (const float*)d_in[10];
  const float* bqkv = (const float*)d_in[11];
  const float* wo = (const float*)d_in[12];
  const float* bo = (const float*)d_in[13];
  const float* ln2_g = (const float*)d_in[14];
  const float* ln2_b = (const float*)d_in[15];
  const float* w1 = (const float*)d_in[16];
  const float* b1 = (const float*)d_in[17];
  const float* w2 = (const float*)d_in[18];
  const float* b2 = (const float*)d_in[19];
  float* out = (float*)d_out;

  uint8_t* p = (uint8_t*)d_ws;
  float* weightsv = (float*)p; p += (size_t)TOKN * 4;
  int* selv = (int*)p;         p += (size_t)TOKN * 4;
  int* idxlv = (int*)p;        p += (size_t)TOKN * 4;
  int* gidxv = (int*)p;        p += (size_t)TOKN * 4;
  int* cntv = (int*)p;         p += 64 * 4;
  int* startv = (int*)p;       p += 64 * 4;
  int* mtotv = (int*)p;        p += 64 * 4;
  short* wqkvt = (short*)p;    p += (size_t)768 * 256 * 2;
  short* wot = (short*)p;      p += (size_t)256 * 256 * 2;
  short* w1t = (short*)p;      p += (size_t)1024 * 256 * 2;
  short* w2t = (short*)p;      p += (size_t)256 * 1024 * 2;
  float* h1v = (float*)p;      p += (size_t)TOKN * 256 * 4;
  short* h2nv = (short*)p;     p += (size_t)TOKN * 256 * 2;
  short* ctxv = (short*)p;     p += (size_t)TOKN * 256 * 2;
  uint8_t* R = p;
  short* xnv = (short*)R;
  short* qkvv = (short*)(R + (size_t)TOKN * 256 * 2);
  short* actv = (short*)R;

  convw_k<<<dim3(1024), dim3(256), 0, stream>>>(wqkv, wo, w1, w2, wqkvt, wot, w1t, w2t);
  ln_router_k<<<dim3(TOKN / 4), dim3(256), 0, stream>>>(x, ln1_g, ln1_b, wp_w, wp_b,
                                                        xnv, weightsv, out);
  router_gemm_k<<<dim3(360), dim3(256), 0, stream>>>(x, a1_w, a1_b, a2_w, a2_b, selv);
  scanA_k<<<dim3(64), dim3(512), 0, stream>>>(selv, idxlv, cntv);
  scanB_k<<<dim3(1), dim3(512), 0, stream>>>(cntv, startv, mtotv, gidxv,
                                             out + (size_t)TOKN * 256);
  scanC_k<<<dim3(64), dim3(512), 0, stream>>>(idxlv, startv, cntv, gidxv);
  gemm_bt_k<0><<<dim3(12, 360), dim3(256), 0, stream>>>(
      xnv, wqkvt, bqkv, nullptr, nullptr, gidxv, mtotv, qkvv, nullptr, 768, 256);
  attn_k<<<dim3(1024), dim3(256), 0, stream>>>(qkvv, amask, gidxv, startv, cntv, ctxv);
  gemm_bt_k<1><<<dim3(4, 360), dim3(256), 0, stream>>>(
      ctxv, wot, bo, x, nullptr, gidxv, mtotv, nullptr, h1v, 256, 256);
  ln_k<<<dim3(TOKN / 4), dim3(256), 0, stream>>>(h1v, ln2_g, ln2_b, mtotv, h2nv);
  gemm_bt_k<2><<<dim3(16, 360), dim3(256), 0, stream>>>(
      h2nv, w1t, b1, nullptr, nullptr, gidxv, mtotv, actv, nullptr, 1024, 256);
  gemm_bt_k<3><<<dim3(4, 360), dim3(256), 0, stream>>>(
      actv, w2t, b2, h1v, weightsv, gidxv, mtotv, nullptr, out, 256, 1024);
}